// Round 1
// baseline (626.863 us; speedup 1.0000x reference)
//
#include <hip/hip_runtime.h>

#define B_SZ 2
#define L_SEQ 2048
#define E_DIM 1024
#define NH 16
#define DH 64
#define DFF_DIM 4096
#define ROWS (B_SZ * L_SEQ)  // 4096

typedef __attribute__((ext_vector_type(8))) short short8;
typedef __attribute__((ext_vector_type(4))) float f32x4;

// ---- bf16 <-> f32 helpers (manual RNE, no header union issues) ----
__device__ __forceinline__ short f2bf(float f) {
  unsigned u = __builtin_bit_cast(unsigned, f);
  u = (u + 0x7FFFu + ((u >> 16) & 1u)) >> 16;
  return (short)u;
}
__device__ __forceinline__ float bf2f(short s) {
  unsigned u = ((unsigned)(unsigned short)s) << 16;
  return __builtin_bit_cast(float, u);
}

// ---- async global->LDS 16B copy ----
__device__ __forceinline__ void async_copy16(const void* g, void* l) {
  __builtin_amdgcn_global_load_lds(
      (const __attribute__((address_space(1))) void*)g,
      (__attribute__((address_space(3))) void*)l, 16, 0, 0);
}

// ---- weight transpose+convert: W (K x N, f32) -> Wt (N x K, bf16) ----
__global__ __launch_bounds__(256) void transpose_f32_to_bf16(
    const float* __restrict__ W, short* __restrict__ Wt, int K, int N) {
  __shared__ float tile[32][33];
  int n0 = blockIdx.x * 32, k0 = blockIdx.y * 32;
  int tx = threadIdx.x & 31, ty = threadIdx.x >> 5;  // 32 x 8
#pragma unroll
  for (int i = 0; i < 4; i++)
    tile[ty + 8 * i][tx] = W[(size_t)(k0 + ty + 8 * i) * N + n0 + tx];
  __syncthreads();
#pragma unroll
  for (int i = 0; i < 4; i++)
    Wt[(size_t)(n0 + ty + 8 * i) * K + k0 + tx] = f2bf(tile[tx][ty + 8 * i]);
}

// ---- block reduction over 256 threads (4 waves) ----
__device__ __forceinline__ float block_sum256(float v) {
  __shared__ float sbuf[4];
#pragma unroll
  for (int off = 32; off > 0; off >>= 1) v += __shfl_xor(v, off, 64);
  int lane = threadIdx.x & 63, w = threadIdx.x >> 6;
  if (lane == 0) sbuf[w] = v;
  __syncthreads();
  return sbuf[0] + sbuf[1] + sbuf[2] + sbuf[3];
}

// ---- h = rmsnorm(X) -> bf16 ----
__global__ __launch_bounds__(256) void rmsnorm_k(const float* __restrict__ X,
                                                 short* __restrict__ H) {
  size_t row = blockIdx.x;
  const float4* x4 = (const float4*)(X + row * E_DIM);
  float4 v = x4[threadIdx.x];
  float ss = v.x * v.x + v.y * v.y + v.z * v.z + v.w * v.w;
  ss = block_sum256(ss);
  float inv = rsqrtf(ss * (1.0f / E_DIM));
  short* h = H + row * E_DIM + (size_t)threadIdx.x * 4;
  h[0] = f2bf(v.x * inv);
  h[1] = f2bf(v.y * inv);
  h[2] = f2bf(v.z * inv);
  h[3] = f2bf(v.w * inv);
}

// ---- X2 = X1*(1+1/rms) (in-place), h2 = X1/rms (bf16). rmsnorm(X2)==X1/rms ----
__global__ __launch_bounds__(256) void resid_rms_k(float* __restrict__ X,
                                                   short* __restrict__ H) {
  size_t row = blockIdx.x;
  float4* x4 = (float4*)(X + row * E_DIM);
  float4 v = x4[threadIdx.x];
  float ss = v.x * v.x + v.y * v.y + v.z * v.z + v.w * v.w;
  ss = block_sum256(ss);
  float inv = rsqrtf(ss * (1.0f / E_DIM));
  float4 o;
  o.x = v.x * (1.0f + inv);
  o.y = v.y * (1.0f + inv);
  o.z = v.z * (1.0f + inv);
  o.w = v.w * (1.0f + inv);
  x4[threadIdx.x] = o;
  short* h = H + row * E_DIM + (size_t)threadIdx.x * 4;
  h[0] = f2bf(v.x * inv);
  h[1] = f2bf(v.y * inv);
  h[2] = f2bf(v.z * inv);
  h[3] = f2bf(v.w * inv);
}

// ---- GEMM: C(MxN) = A(MxK bf16) @ Bt(NxK bf16)^T, fused epilogues ----
// epi: 0 = bf16 out (+bias), 1 = gelu->bf16, 2 = (*mul)->bf16, 3 = (+res) f32
__global__ __launch_bounds__(256, 2) void gemm_bt(
    const short* __restrict__ A, const short* __restrict__ Bt,
    const float* __restrict__ bias, const float* __restrict__ res,
    const short* __restrict__ mul, void* __restrict__ out, int M, int N, int K,
    int epi) {
  __shared__ short As[128 * 32];
  __shared__ short Bs[128 * 32];
  int t = threadIdx.x;
  int lane = t & 63;
  int quad = lane >> 4, l16 = lane & 15;
  int wave = t >> 6;
  int wr = wave >> 1, wc = wave & 1;
  int m0 = blockIdx.y * 128, n0 = blockIdx.x * 128;

  f32x4 acc[4][4];
#pragma unroll
  for (int i = 0; i < 4; i++)
#pragma unroll
    for (int j = 0; j < 4; j++) acc[i][j] = (f32x4){0.f, 0.f, 0.f, 0.f};

  for (int k0 = 0; k0 < K; k0 += 32) {
    __syncthreads();
#pragma unroll
    for (int p = 0; p < 2; p++) {
      int s = p * 256 + t;
      int mm = s >> 2, kk = (s & 3) * 8;
      async_copy16(A + (size_t)(m0 + mm) * K + k0 + kk,
                   (char*)As + (size_t)s * 16);
      async_copy16(Bt + (size_t)(n0 + mm) * K + k0 + kk,
                   (char*)Bs + (size_t)s * 16);
    }
    __syncthreads();
    short8 af[4], bfv[4];
#pragma unroll
    for (int i = 0; i < 4; i++) {
      af[i] = *(const short8*)&As[(wr * 64 + i * 16 + l16) * 32 + quad * 8];
      bfv[i] = *(const short8*)&Bs[(wc * 64 + i * 16 + l16) * 32 + quad * 8];
    }
#pragma unroll
    for (int mi = 0; mi < 4; mi++)
#pragma unroll
      for (int ni = 0; ni < 4; ni++)
        acc[mi][ni] = __builtin_amdgcn_mfma_f32_16x16x32_bf16(
            af[mi], bfv[ni], acc[mi][ni], 0, 0, 0);
  }

#pragma unroll
  for (int mi = 0; mi < 4; mi++) {
#pragma unroll
    for (int ni = 0; ni < 4; ni++) {
      int col = n0 + wc * 64 + ni * 16 + l16;
      float bv = bias ? bias[col] : 0.0f;
#pragma unroll
      for (int r = 0; r < 4; r++) {
        int row = m0 + wr * 64 + mi * 16 + quad * 4 + r;
        size_t idx = (size_t)row * N + col;
        float v = acc[mi][ni][r] + bv;
        if (epi == 0) {
          ((short*)out)[idx] = f2bf(v);
        } else if (epi == 1) {
          float g = 0.5f * v * (1.0f + erff(v * 0.70710678118654752f));
          ((short*)out)[idx] = f2bf(g);
        } else if (epi == 2) {
          ((short*)out)[idx] = f2bf(v * bf2f(mul[idx]));
        } else {
          ((float*)out)[idx] = v + res[idx];
        }
      }
    }
  }
}

// ---- flash attention w/ ALiBi + causal ----
// qkv: [B*L][3*H*D] bf16, col = h*192 + t*64 + d ; ctx: [B*L][H*D] bf16
__global__ __launch_bounds__(256) void attn_k(const short* __restrict__ qkv,
                                              short* __restrict__ ctx) {
  int qt = blockIdx.x;        // 64-row q tile
  int bh = blockIdx.y;        // b*NH + h
  int b = bh >> 4, h = bh & 15;
  int t = threadIdx.x;
  int wave = t >> 6, lane = t & 63;
  int quad = lane >> 4, l16 = lane & 15;

  __shared__ short kt[64 * 72];      // K tile [j][d], pad 72
  __shared__ short vt[64 * 72];      // V^T tile [d][j], pad 72
  __shared__ short pb[4 * 16 * 72];  // per-wave P [q][j]

  const float slope = exp2f(-(1.0f + (7.0f / 15.0f) * (float)h));
  const size_t rowstride = 3 * NH * DH;  // 3072
  const short* base = qkv + (size_t)(b * L_SEQ) * rowstride + h * (3 * DH);
  int i0 = qt * 64;
  int iw = i0 + wave * 16;

  // Q fragments (A-operand layout), held in registers for the whole loop
  short8 qf[2];
  {
    const short* qp = base + (size_t)(iw + l16) * rowstride + quad * 8;
    qf[0] = *(const short8*)(qp);
    qf[1] = *(const short8*)(qp + 32);
  }

  f32x4 o[4];
#pragma unroll
  for (int i = 0; i < 4; i++) o[i] = (f32x4){0.f, 0.f, 0.f, 0.f};
  float m_i[4], l_i[4];
#pragma unroll
  for (int r = 0; r < 4; r++) {
    m_i[r] = -1e30f;
    l_i[r] = 0.f;
  }

  short* pw = &pb[wave * 16 * 72];
  int ntile = qt + 1;
  for (int tix = 0; tix < ntile; ++tix) {
    int j0 = tix * 64;
    __syncthreads();
    {  // stage K tile and V^T tile cooperatively
      int jr = t >> 3, dc = (t & 7) * 8;
      const short* kg = base + DH;
      const short* vg = base + 2 * DH;
#pragma unroll
      for (int p = 0; p < 2; p++) {
        int j = jr + p * 32;
        short8 kv = *(const short8*)(kg + (size_t)(j0 + j) * rowstride + dc);
        *(short8*)&kt[j * 72 + dc] = kv;
        short8 vv = *(const short8*)(vg + (size_t)(j0 + j) * rowstride + dc);
#pragma unroll
        for (int u = 0; u < 8; u++) vt[(dc + u) * 72 + j] = vv[u];
      }
    }
    __syncthreads();

    // S = Q K^T (16 rows x 64 cols per wave)
    f32x4 s[4];
#pragma unroll
    for (int nt = 0; nt < 4; nt++) {
      f32x4 a = (f32x4){0.f, 0.f, 0.f, 0.f};
#pragma unroll
      for (int ks = 0; ks < 2; ks++) {
        short8 bf =
            *(const short8*)&kt[(nt * 16 + l16) * 72 + ks * 32 + quad * 8];
        a = __builtin_amdgcn_mfma_f32_16x16x32_bf16(qf[ks], bf, a, 0, 0, 0);
      }
      s[nt] = a;
    }
    // scale + alibi + causal mask
#pragma unroll
    for (int nt = 0; nt < 4; nt++) {
      int j = j0 + nt * 16 + l16;
#pragma unroll
      for (int r = 0; r < 4; r++) {
        int i = iw + quad * 4 + r;
        float v = s[nt][r] * 0.125f + slope * (float)(j - i);
        s[nt][r] = (j <= i) ? v : -1e30f;
      }
    }
    // online softmax update
    float al[4];
#pragma unroll
    for (int r = 0; r < 4; r++) {
      float mx = fmaxf(fmaxf(s[0][r], s[1][r]), fmaxf(s[2][r], s[3][r]));
#pragma unroll
      for (int off = 8; off > 0; off >>= 1)
        mx = fmaxf(mx, __shfl_xor(mx, off, 64));
      float mnew = fmaxf(m_i[r], mx);
      al[r] = __expf(m_i[r] - mnew);
      m_i[r] = mnew;
    }
    float rs[4] = {0.f, 0.f, 0.f, 0.f};
#pragma unroll
    for (int nt = 0; nt < 4; nt++) {
#pragma unroll
      for (int r = 0; r < 4; r++) {
        float p = __expf(s[nt][r] - m_i[r]);
        rs[r] += p;
        pw[(quad * 4 + r) * 72 + nt * 16 + l16] = f2bf(p);
      }
    }
#pragma unroll
    for (int r = 0; r < 4; r++) {
#pragma unroll
      for (int off = 8; off > 0; off >>= 1) rs[r] += __shfl_xor(rs[r], off, 64);
      l_i[r] = l_i[r] * al[r] + rs[r];
#pragma unroll
      for (int nt = 0; nt < 4; nt++) o[nt][r] *= al[r];
    }
    // O += P V  (P round-trips LDS into A-operand layout)
    short8 pf[2];
    pf[0] = *(const short8*)&pw[l16 * 72 + quad * 8];
    pf[1] = *(const short8*)&pw[l16 * 72 + 32 + quad * 8];
#pragma unroll
    for (int nt = 0; nt < 4; nt++) {
#pragma unroll
      for (int ks = 0; ks < 2; ks++) {
        short8 bv =
            *(const short8*)&vt[(nt * 16 + l16) * 72 + ks * 32 + quad * 8];
        o[nt] = __builtin_amdgcn_mfma_f32_16x16x32_bf16(pf[ks], bv, o[nt], 0,
                                                        0, 0);
      }
    }
  }
  // epilogue: O /= l, store ctx bf16
#pragma unroll
  for (int r = 0; r < 4; r++) {
    float inv = 1.0f / l_i[r];
    int i = iw + quad * 4 + r;
    short* dst = ctx + (size_t)(b * L_SEQ + i) * (NH * DH) + h * DH;
#pragma unroll
    for (int nt = 0; nt < 4; nt++)
      dst[nt * 16 + l16] = f2bf(o[nt][r] * inv);
  }
}

extern "C" void kernel_launch(void* const* d_in, const int* in_sizes, int n_in,
                              void* d_out, int out_size, void* d_ws,
                              size_t ws_size, hipStream_t stream) {
  const float* X = (const float*)d_in[0];
  // d_in[1] encoder_out, d_in[6..11] cross-attn params: unused by reference
  const float* Wqkv = (const float*)d_in[2];
  const float* bqkv = (const float*)d_in[3];
  const float* Wo_sa = (const float*)d_in[4];
  const float* bo_sa = (const float*)d_in[5];
  const float* Ww = (const float*)d_in[12];
  const float* Wv = (const float*)d_in[13];
  const float* Wout = (const float*)d_in[14];

  char* ws = (char*)d_ws;
  auto take = [&](size_t bytes) {
    char* p = ws;
    ws += (bytes + 255) & ~(size_t)255;
    return p;
  };
  short* WqkvT = (short*)take((size_t)3 * NH * DH * E_DIM * 2);  // 3072x1024
  short* WoT = (short*)take((size_t)E_DIM * E_DIM * 2);          // 1024x1024
  short* WwT = (short*)take((size_t)DFF_DIM * E_DIM * 2);        // 4096x1024
  short* WvT = (short*)take((size_t)DFF_DIM * E_DIM * 2);
  short* WoutT = (short*)take((size_t)E_DIM * DFF_DIM * 2);      // 1024x4096
  short* Hbuf = (short*)take((size_t)ROWS * E_DIM * 2);
  short* QKV = (short*)take((size_t)ROWS * 3 * NH * DH * 2);
  short* CTX = (short*)take((size_t)ROWS * NH * DH * 2);
  float* X1 = (float*)take((size_t)ROWS * E_DIM * 4);
  short* GA = (short*)take((size_t)ROWS * DFF_DIM * 2);
  short* FF = (short*)take((size_t)ROWS * DFF_DIM * 2);
  (void)ws_size;
  (void)in_sizes;
  (void)n_in;
  (void)out_size;

  dim3 blk(256);
  // weight transpose/convert (K x N f32 -> N x K bf16)
  transpose_f32_to_bf16<<<dim3(3072 / 32, 1024 / 32), blk, 0, stream>>>(
      Wqkv, WqkvT, 1024, 3072);
  transpose_f32_to_bf16<<<dim3(1024 / 32, 1024 / 32), blk, 0, stream>>>(
      Wo_sa, WoT, 1024, 1024);
  transpose_f32_to_bf16<<<dim3(4096 / 32, 1024 / 32), blk, 0, stream>>>(
      Ww, WwT, 1024, 4096);
  transpose_f32_to_bf16<<<dim3(4096 / 32, 1024 / 32), blk, 0, stream>>>(
      Wv, WvT, 1024, 4096);
  transpose_f32_to_bf16<<<dim3(1024 / 32, 4096 / 32), blk, 0, stream>>>(
      Wout, WoutT, 4096, 1024);

  // h = rmsnorm(X)
  rmsnorm_k<<<ROWS, blk, 0, stream>>>(X, Hbuf);
  // qkv = h @ Wqkv + bqkv  -> bf16
  gemm_bt<<<dim3(3072 / 128, ROWS / 128), blk, 0, stream>>>(
      Hbuf, WqkvT, bqkv, nullptr, nullptr, QKV, ROWS, 3072, 1024, 0);
  // attention -> ctx bf16
  attn_k<<<dim3(L_SEQ / 64, B_SZ * NH), blk, 0, stream>>>(QKV, CTX);
  // X1 = X + ctx @ Wo_sa + bo_sa  (f32)
  gemm_bt<<<dim3(1024 / 128, ROWS / 128), blk, 0, stream>>>(
      CTX, WoT, bo_sa, X, nullptr, X1, ROWS, 1024, 1024, 3);
  // X2 = X1*(1+1/rms) in-place; h2 = X1/rms
  resid_rms_k<<<ROWS, blk, 0, stream>>>(X1, Hbuf);
  // ga = gelu(h2 @ Ww)  -> bf16
  gemm_bt<<<dim3(4096 / 128, ROWS / 128), blk, 0, stream>>>(
      Hbuf, WwT, nullptr, nullptr, nullptr, GA, ROWS, 4096, 1024, 1);
  // ff = (h2 @ Wv) * ga -> bf16
  gemm_bt<<<dim3(4096 / 128, ROWS / 128), blk, 0, stream>>>(
      Hbuf, WvT, nullptr, nullptr, GA, FF, ROWS, 4096, 1024, 2);
  // out = X2 + ff @ Wout  (f32)
  gemm_bt<<<dim3(1024 / 128, ROWS / 128), blk, 0, stream>>>(
      FF, WoutT, nullptr, X1, nullptr, (float*)d_out, ROWS, 1024, 4096, 3);
}

// Round 2
// 569.793 us; speedup vs baseline: 1.1002x; 1.1002x over previous
//
#include <hip/hip_runtime.h>

#define B_SZ 2
#define L_SEQ 2048
#define E_DIM 1024
#define NH 16
#define DH 64
#define DFF_DIM 4096
#define ROWS (B_SZ * L_SEQ)  // 4096

typedef __attribute__((ext_vector_type(8))) short short8;
typedef __attribute__((ext_vector_type(4))) float f32x4;

// ---- bf16 <-> f32 helpers ----
__device__ __forceinline__ short f2bf(float f) {
  unsigned u = __builtin_bit_cast(unsigned, f);
  u = (u + 0x7FFFu + ((u >> 16) & 1u)) >> 16;
  return (short)u;
}
__device__ __forceinline__ float bf2f(short s) {
  unsigned u = ((unsigned)(unsigned short)s) << 16;
  return __builtin_bit_cast(float, u);
}

// ---- async global->LDS 16B copy ----
__device__ __forceinline__ void async_copy16(const void* g, void* l) {
  __builtin_amdgcn_global_load_lds(
      (const __attribute__((address_space(1))) void*)g,
      (__attribute__((address_space(3))) void*)l, 16, 0, 0);
}

// ---- weight transpose+convert: W (K x N, f32) -> Wt (N x K, bf16) ----
__global__ __launch_bounds__(256) void transpose_f32_to_bf16(
    const float* __restrict__ W, short* __restrict__ Wt, int K, int N) {
  __shared__ float tile[32][33];
  int n0 = blockIdx.x * 32, k0 = blockIdx.y * 32;
  int tx = threadIdx.x & 31, ty = threadIdx.x >> 5;  // 32 x 8
#pragma unroll
  for (int i = 0; i < 4; i++)
    tile[ty + 8 * i][tx] = W[(size_t)(k0 + ty + 8 * i) * N + n0 + tx];
  __syncthreads();
#pragma unroll
  for (int i = 0; i < 4; i++)
    Wt[(size_t)(n0 + ty + 8 * i) * K + k0 + tx] = f2bf(tile[tx][ty + 8 * i]);
}

// ---- block reduction over 256 threads (4 waves) ----
__device__ __forceinline__ float block_sum256(float v) {
  __shared__ float sbuf[4];
#pragma unroll
  for (int off = 32; off > 0; off >>= 1) v += __shfl_xor(v, off, 64);
  int lane = threadIdx.x & 63, w = threadIdx.x >> 6;
  if (lane == 0) sbuf[w] = v;
  __syncthreads();
  return sbuf[0] + sbuf[1] + sbuf[2] + sbuf[3];
}

// ---- h = rmsnorm(X) -> bf16 ----
__global__ __launch_bounds__(256) void rmsnorm_k(const float* __restrict__ X,
                                                 short* __restrict__ H) {
  size_t row = blockIdx.x;
  const float4* x4 = (const float4*)(X + row * E_DIM);
  float4 v = x4[threadIdx.x];
  float ss = v.x * v.x + v.y * v.y + v.z * v.z + v.w * v.w;
  ss = block_sum256(ss);
  float inv = rsqrtf(ss * (1.0f / E_DIM));
  short* h = H + row * E_DIM + (size_t)threadIdx.x * 4;
  h[0] = f2bf(v.x * inv);
  h[1] = f2bf(v.y * inv);
  h[2] = f2bf(v.z * inv);
  h[3] = f2bf(v.w * inv);
}

// ---- X2 = X1*(1+1/rms) in-place; h2 = X1/rms (rmsnorm(X2)==X1/rms) ----
__global__ __launch_bounds__(256) void resid_rms_k(float* __restrict__ X,
                                                   short* __restrict__ H) {
  size_t row = blockIdx.x;
  float4* x4 = (float4*)(X + row * E_DIM);
  float4 v = x4[threadIdx.x];
  float ss = v.x * v.x + v.y * v.y + v.z * v.z + v.w * v.w;
  ss = block_sum256(ss);
  float inv = rsqrtf(ss * (1.0f / E_DIM));
  float4 o;
  o.x = v.x * (1.0f + inv);
  o.y = v.y * (1.0f + inv);
  o.z = v.z * (1.0f + inv);
  o.w = v.w * (1.0f + inv);
  x4[threadIdx.x] = o;
  short* h = H + row * E_DIM + (size_t)threadIdx.x * 4;
  h[0] = f2bf(v.x * inv);
  h[1] = f2bf(v.y * inv);
  h[2] = f2bf(v.z * inv);
  h[3] = f2bf(v.w * inv);
}

// ---- GEMM: C(MxN) = A(MxK bf16) @ Bt(NxK bf16)^T, fused epilogues ----
// epi: 0 = bf16 out (+bias), 1 = gelu->bf16, 2 = (*mul)->bf16, 3 = (+res) f32
__global__ __launch_bounds__(256, 2) void gemm_bt(
    const short* __restrict__ A, const short* __restrict__ Bt,
    const float* __restrict__ bias, const float* __restrict__ res,
    const short* __restrict__ mul, void* __restrict__ out, int M, int N, int K,
    int epi) {
  __shared__ short As[128 * 32];
  __shared__ short Bs[128 * 32];
  int t = threadIdx.x;
  int lane = t & 63;
  int quad = lane >> 4, l16 = lane & 15;
  int wave = t >> 6;
  int wr = wave >> 1, wc = wave & 1;
  int m0 = blockIdx.y * 128, n0 = blockIdx.x * 128;

  f32x4 acc[4][4];
#pragma unroll
  for (int i = 0; i < 4; i++)
#pragma unroll
    for (int j = 0; j < 4; j++) acc[i][j] = (f32x4){0.f, 0.f, 0.f, 0.f};

  for (int k0 = 0; k0 < K; k0 += 32) {
    __syncthreads();
#pragma unroll
    for (int p = 0; p < 2; p++) {
      int s = p * 256 + t;
      int mm = s >> 2, kk = (s & 3) * 8;
      async_copy16(A + (size_t)(m0 + mm) * K + k0 + kk,
                   (char*)As + (size_t)s * 16);
      async_copy16(Bt + (size_t)(n0 + mm) * K + k0 + kk,
                   (char*)Bs + (size_t)s * 16);
    }
    __syncthreads();
    short8 af[4], bfv[4];
#pragma unroll
    for (int i = 0; i < 4; i++) {
      af[i] = *(const short8*)&As[(wr * 64 + i * 16 + l16) * 32 + quad * 8];
      bfv[i] = *(const short8*)&Bs[(wc * 64 + i * 16 + l16) * 32 + quad * 8];
    }
#pragma unroll
    for (int mi = 0; mi < 4; mi++)
#pragma unroll
      for (int ni = 0; ni < 4; ni++)
        acc[mi][ni] = __builtin_amdgcn_mfma_f32_16x16x32_bf16(
            af[mi], bfv[ni], acc[mi][ni], 0, 0, 0);
  }

#pragma unroll
  for (int mi = 0; mi < 4; mi++) {
#pragma unroll
    for (int ni = 0; ni < 4; ni++) {
      int col = n0 + wc * 64 + ni * 16 + l16;
      float bv = bias ? bias[col] : 0.0f;
#pragma unroll
      for (int r = 0; r < 4; r++) {
        int row = m0 + wr * 64 + mi * 16 + quad * 4 + r;
        size_t idx = (size_t)row * N + col;
        float v = acc[mi][ni][r] + bv;
        if (epi == 0) {
          ((short*)out)[idx] = f2bf(v);
        } else if (epi == 1) {
          float g = 0.5f * v * (1.0f + erff(v * 0.70710678118654752f));
          ((short*)out)[idx] = f2bf(g);
        } else if (epi == 2) {
          ((short*)out)[idx] = f2bf(v * bf2f(mul[idx]));
        } else {
          ((float*)out)[idx] = v + res[idx];
        }
      }
    }
  }
}

// ---- K/V prep: Kh[bh][l][d] copy; VTh[bh][d][l] transpose ----
__global__ __launch_bounds__(256) void kv_prep(const short* __restrict__ qkv,
                                               short* __restrict__ Kh,
                                               short* __restrict__ VTh) {
  int lt = blockIdx.x, bh = blockIdx.y;
  int b = bh >> 4, h = bh & 15;
  __shared__ short vtile[64 * 72];
  int t = threadIdx.x;
  int r = t >> 3, c = (t & 7) * 8;
  const short* base =
      qkv + (size_t)(b * L_SEQ + lt * 64) * (3 * NH * DH) + h * (3 * DH);
#pragma unroll
  for (int p = 0; p < 2; p++) {
    int row = r + p * 32;
    short8 kv = *(const short8*)(base + (size_t)row * (3 * NH * DH) + DH + c);
    *(short8*)(Kh + ((size_t)bh * L_SEQ + lt * 64 + row) * DH + c) = kv;
    short8 vv =
        *(const short8*)(base + (size_t)row * (3 * NH * DH) + 2 * DH + c);
    *(short8*)&vtile[row * 72 + c] = vv;
  }
  __syncthreads();
#pragma unroll
  for (int p = 0; p < 2; p++) {
    int d = r + p * 32;
    short8 o;
#pragma unroll
    for (int u = 0; u < 8; u++) o[u] = vtile[(c + u) * 72 + d];
    *(short8*)(VTh + ((size_t)bh * DH + d) * L_SEQ + lt * 64 + c) = o;
  }
}

// ---- flash attention, constant-m online softmax (m = 8, shift-invariant) ----
__global__ __launch_bounds__(256) void attn_k(const short* __restrict__ qkv,
                                              const short* __restrict__ Kh,
                                              const short* __restrict__ VTh,
                                              short* __restrict__ ctx) {
  int qt = (gridDim.x - 1) - blockIdx.x;  // longest blocks first
  int bh = blockIdx.y;
  int b = bh >> 4, h = bh & 15;
  int t = threadIdx.x;
  int wave = t >> 6, lane = t & 63;
  int quad = lane >> 4, l16 = lane & 15;

  __shared__ short kt[64 * 72];      // K tile [j][d], pad 72
  __shared__ short vt[64 * 72];      // V^T tile [d][j], pad 72
  __shared__ short pb[4 * 16 * 70];  // per-wave P [q][j], pad 70

  const float slope = exp2f(-(1.0f + (7.0f / 15.0f) * (float)h));
  const size_t rowstride = 3 * NH * DH;  // 3072
  const short* qbase = qkv + (size_t)(b * L_SEQ) * rowstride + h * (3 * DH);
  int iw = qt * 64 + wave * 16;

  // Q fragments (A-operand layout), registers for whole loop
  short8 qf[2];
  {
    const short* qp = qbase + (size_t)(iw + l16) * rowstride + quad * 8;
    qf[0] = *(const short8*)(qp);
    qf[1] = *(const short8*)(qp + 32);
  }

  f32x4 o[4];
#pragma unroll
  for (int i = 0; i < 4; i++) o[i] = (f32x4){0.f, 0.f, 0.f, 0.f};
  float rs[4] = {0.f, 0.f, 0.f, 0.f};
  // per-row constant part: -slope*i - 8
  float crow[4];
  int irow[4];
#pragma unroll
  for (int r = 0; r < 4; r++) {
    irow[r] = iw + quad * 4 + r;
    crow[r] = -slope * (float)irow[r] - 8.0f;
  }

  // staging map: 8 lanes per 64-elem row
  int sr = t >> 3, sc = (t & 7) * 8;
  const short* kg = Kh + (size_t)bh * L_SEQ * DH;
  const short* vg = VTh + (size_t)bh * DH * L_SEQ;
  short8 kreg[2], vreg[2];
  auto loadKV = [&](int j0) {
    kreg[0] = *(const short8*)(kg + (size_t)(j0 + sr) * DH + sc);
    kreg[1] = *(const short8*)(kg + (size_t)(j0 + sr + 32) * DH + sc);
    vreg[0] = *(const short8*)(vg + (size_t)sr * L_SEQ + j0 + sc);
    vreg[1] = *(const short8*)(vg + (size_t)(sr + 32) * L_SEQ + j0 + sc);
  };
  loadKV(0);

  short* pw = &pb[wave * 16 * 70];
  int ntile = qt + 1;
  for (int tix = 0; tix < ntile; ++tix) {
    int j0 = tix * 64;
    __syncthreads();  // all waves done reading previous tile
    *(short8*)&kt[sr * 72 + sc] = kreg[0];
    *(short8*)&kt[(sr + 32) * 72 + sc] = kreg[1];
    *(short8*)&vt[sr * 72 + sc] = vreg[0];
    *(short8*)&vt[(sr + 32) * 72 + sc] = vreg[1];
    __syncthreads();
    if (tix + 1 < ntile) loadKV(j0 + 64);  // prefetch overlaps compute

    // S = Q K^T (16 rows x 64 cols per wave)
    f32x4 s[4];
#pragma unroll
    for (int nt = 0; nt < 4; nt++) {
      f32x4 a = (f32x4){0.f, 0.f, 0.f, 0.f};
#pragma unroll
      for (int ks = 0; ks < 2; ks++) {
        short8 bf =
            *(const short8*)&kt[(nt * 16 + l16) * 72 + ks * 32 + quad * 8];
        a = __builtin_amdgcn_mfma_f32_16x16x32_bf16(qf[ks], bf, a, 0, 0, 0);
      }
      s[nt] = a;
    }
    // p = exp(S/8 + slope*(j-i) - 8); causal mask only on diagonal tile
    bool diag = (tix == ntile - 1);
#pragma unroll
    for (int nt = 0; nt < 4; nt++) {
      int j = j0 + nt * 16 + l16;
      float jb = slope * (float)j;
#pragma unroll
      for (int r = 0; r < 4; r++) {
        float v = __builtin_fmaf(s[nt][r], 0.125f, jb + crow[r]);
        if (diag && j > irow[r]) v = -1e30f;
        float p = __expf(v);
        rs[r] += p;
        pw[(quad * 4 + r) * 70 + nt * 16 + l16] = f2bf(p);
      }
    }
    // O += P V  (P round-trips LDS into A-operand layout; per-wave, no barrier)
    short8 pf[2];
    pf[0] = *(const short8*)&pw[l16 * 70 + quad * 8];
    pf[1] = *(const short8*)&pw[l16 * 70 + 32 + quad * 8];
#pragma unroll
    for (int nt = 0; nt < 4; nt++) {
#pragma unroll
      for (int ks = 0; ks < 2; ks++) {
        short8 bv =
            *(const short8*)&vt[(nt * 16 + l16) * 72 + ks * 32 + quad * 8];
        o[nt] = __builtin_amdgcn_mfma_f32_16x16x32_bf16(pf[ks], bv, o[nt], 0,
                                                        0, 0);
      }
    }
  }
  // l = butterfly-sum of rs across the 16 j-lanes; store O/l
#pragma unroll
  for (int r = 0; r < 4; r++) {
#pragma unroll
    for (int off = 1; off < 16; off <<= 1) rs[r] += __shfl_xor(rs[r], off, 64);
    float inv = 1.0f / rs[r];
    short* dst = ctx + (size_t)(b * L_SEQ + irow[r]) * (NH * DH) + h * DH;
#pragma unroll
    for (int nt = 0; nt < 4; nt++) dst[nt * 16 + l16] = f2bf(o[nt][r] * inv);
  }
}

extern "C" void kernel_launch(void* const* d_in, const int* in_sizes, int n_in,
                              void* d_out, int out_size, void* d_ws,
                              size_t ws_size, hipStream_t stream) {
  const float* X = (const float*)d_in[0];
  const float* Wqkv = (const float*)d_in[2];
  const float* bqkv = (const float*)d_in[3];
  const float* Wo_sa = (const float*)d_in[4];
  const float* bo_sa = (const float*)d_in[5];
  const float* Ww = (const float*)d_in[12];
  const float* Wv = (const float*)d_in[13];
  const float* Wout = (const float*)d_in[14];

  char* ws = (char*)d_ws;
  auto take = [&](size_t bytes) {
    char* p = ws;
    ws += (bytes + 255) & ~(size_t)255;
    return p;
  };
  short* WqkvT = (short*)take((size_t)3 * NH * DH * E_DIM * 2);  // 6 MB
  short* WoT = (short*)take((size_t)E_DIM * E_DIM * 2);          // 2 MB
  short* WwT = (short*)take((size_t)DFF_DIM * E_DIM * 2);        // 8 MB
  short* WvT = (short*)take((size_t)DFF_DIM * E_DIM * 2);        // 8 MB
  short* WoutT = (short*)take((size_t)E_DIM * DFF_DIM * 2);      // 8 MB
  short* Hbuf = (short*)take((size_t)ROWS * E_DIM * 2);          // 8 MB
  short* QKV = (short*)take((size_t)ROWS * 3 * NH * DH * 2);     // 24 MB
  short* CTX = (short*)take((size_t)ROWS * NH * DH * 2);         // 8 MB
  float* X1 = (float*)take((size_t)ROWS * E_DIM * 4);            // 16 MB
  short* GA = (short*)take((size_t)ROWS * DFF_DIM * 2);          // 32 MB
  short* FF = (short*)take((size_t)ROWS * DFF_DIM * 2);          // 32 MB
  // Kh/VTh alias GA (GA written only after attention completes)
  short* Kh = GA;                                        // 8 MB
  short* VTh = GA + (size_t)B_SZ * NH * L_SEQ * DH;      // 8 MB
  (void)ws_size;
  (void)in_sizes;
  (void)n_in;
  (void)out_size;

  dim3 blk(256);
  transpose_f32_to_bf16<<<dim3(3072 / 32, 1024 / 32), blk, 0, stream>>>(
      Wqkv, WqkvT, 1024, 3072);
  transpose_f32_to_bf16<<<dim3(1024 / 32, 1024 / 32), blk, 0, stream>>>(
      Wo_sa, WoT, 1024, 1024);
  transpose_f32_to_bf16<<<dim3(4096 / 32, 1024 / 32), blk, 0, stream>>>(
      Ww, WwT, 1024, 4096);
  transpose_f32_to_bf16<<<dim3(4096 / 32, 1024 / 32), blk, 0, stream>>>(
      Wv, WvT, 1024, 4096);
  transpose_f32_to_bf16<<<dim3(1024 / 32, 4096 / 32), blk, 0, stream>>>(
      Wout, WoutT, 4096, 1024);

  rmsnorm_k<<<ROWS, blk, 0, stream>>>(X, Hbuf);
  gemm_bt<<<dim3(3072 / 128, ROWS / 128), blk, 0, stream>>>(
      Hbuf, WqkvT, bqkv, nullptr, nullptr, QKV, ROWS, 3072, 1024, 0);
  kv_prep<<<dim3(L_SEQ / 64, B_SZ * NH), blk, 0, stream>>>(QKV, Kh, VTh);
  attn_k<<<dim3(L_SEQ / 64, B_SZ * NH), blk, 0, stream>>>(QKV, Kh, VTh, CTX);
  gemm_bt<<<dim3(1024 / 128, ROWS / 128), blk, 0, stream>>>(
      CTX, WoT, bo_sa, X, nullptr, X1, ROWS, 1024, 1024, 3);
  resid_rms_k<<<ROWS, blk, 0, stream>>>(X1, Hbuf);
  gemm_bt<<<dim3(4096 / 128, ROWS / 128), blk, 0, stream>>>(
      Hbuf, WwT, nullptr, nullptr, nullptr, GA, ROWS, 4096, 1024, 1);
  gemm_bt<<<dim3(4096 / 128, ROWS / 128), blk, 0, stream>>>(
      Hbuf, WvT, nullptr, nullptr, GA, FF, ROWS, 4096, 1024, 2);
  gemm_bt<<<dim3(1024 / 128, ROWS / 128), blk, 0, stream>>>(
      FF, WoutT, nullptr, X1, nullptr, (float*)d_out, ROWS, 1024, 4096, 3);
}

// Round 3
// 498.573 us; speedup vs baseline: 1.2573x; 1.1428x over previous
//
#include <hip/hip_runtime.h>

#define B_SZ 2
#define L_SEQ 2048
#define E_DIM 1024
#define NH 16
#define DH 64
#define DFF_DIM 4096
#define ROWS (B_SZ * L_SEQ)  // 4096

typedef __attribute__((ext_vector_type(8))) short short8;
typedef __attribute__((ext_vector_type(4))) float f32x4;

// ---- bf16 <-> f32 helpers ----
__device__ __forceinline__ short f2bf(float f) {
  unsigned u = __builtin_bit_cast(unsigned, f);
  u = (u + 0x7FFFu + ((u >> 16) & 1u)) >> 16;
  return (short)u;
}
__device__ __forceinline__ float bf2f(short s) {
  unsigned u = ((unsigned)(unsigned short)s) << 16;
  return __builtin_bit_cast(float, u);
}

// ---- async global->LDS 16B copy ----
__device__ __forceinline__ void async_copy16(const void* g, void* l) {
  __builtin_amdgcn_global_load_lds(
      (const __attribute__((address_space(1))) void*)g,
      (__attribute__((address_space(3))) void*)l, 16, 0, 0);
}

// ---- weight transpose+convert: W (K x N, f32) -> Wt (rows remapped, bf16)
// poff < 0: out row = n.  poff >= 0: out row = (n/64)*128 + (n%64) + poff
// (interleaves two N x K weights in 64-row pairs for the gated-FFN gemm)
__global__ __launch_bounds__(256) void transpose_f32_to_bf16(
    const float* __restrict__ W, short* __restrict__ Wt, int K, int N,
    int poff) {
  __shared__ float tile[32][33];
  int n0 = blockIdx.x * 32, k0 = blockIdx.y * 32;
  int tx = threadIdx.x & 31, ty = threadIdx.x >> 5;  // 32 x 8
#pragma unroll
  for (int i = 0; i < 4; i++)
    tile[ty + 8 * i][tx] = W[(size_t)(k0 + ty + 8 * i) * N + n0 + tx];
  __syncthreads();
#pragma unroll
  for (int i = 0; i < 4; i++) {
    int n = n0 + ty + 8 * i;
    int orow = (poff < 0) ? n : ((n >> 6) * 128 + (n & 63) + poff);
    Wt[(size_t)orow * K + k0 + tx] = f2bf(tile[tx][ty + 8 * i]);
  }
}

// ---- block reduction over 256 threads (4 waves) ----
__device__ __forceinline__ float block_sum256(float v) {
  __shared__ float sbuf[4];
#pragma unroll
  for (int off = 32; off > 0; off >>= 1) v += __shfl_xor(v, off, 64);
  int lane = threadIdx.x & 63, w = threadIdx.x >> 6;
  if (lane == 0) sbuf[w] = v;
  __syncthreads();
  return sbuf[0] + sbuf[1] + sbuf[2] + sbuf[3];
}

// ---- h = rmsnorm(X) -> bf16 ----
__global__ __launch_bounds__(256) void rmsnorm_k(const float* __restrict__ X,
                                                 short* __restrict__ H) {
  size_t row = blockIdx.x;
  const float4* x4 = (const float4*)(X + row * E_DIM);
  float4 v = x4[threadIdx.x];
  float ss = v.x * v.x + v.y * v.y + v.z * v.z + v.w * v.w;
  ss = block_sum256(ss);
  float inv = rsqrtf(ss * (1.0f / E_DIM));
  short* h = H + row * E_DIM + (size_t)threadIdx.x * 4;
  h[0] = f2bf(v.x * inv);
  h[1] = f2bf(v.y * inv);
  h[2] = f2bf(v.z * inv);
  h[3] = f2bf(v.w * inv);
}

// ---- fused: X1 = X + p0 + p1 + bias; X2 = X1*(1+1/rms); h2 = X1/rms ----
__global__ __launch_bounds__(256) void resid_rms_fused(
    const float* __restrict__ X, const float* __restrict__ P0,
    const float* __restrict__ P1, const float* __restrict__ bias,
    float* __restrict__ Xout, short* __restrict__ H) {
  size_t row = blockIdx.x;
  int t = threadIdx.x;
  float4 v = ((const float4*)(X + row * E_DIM))[t];
  float4 a = ((const float4*)(P0 + row * E_DIM))[t];
  float4 b = ((const float4*)(P1 + row * E_DIM))[t];
  float4 c = ((const float4*)bias)[t];
  v.x += a.x + b.x + c.x;
  v.y += a.y + b.y + c.y;
  v.z += a.z + b.z + c.z;
  v.w += a.w + b.w + c.w;
  float ss = v.x * v.x + v.y * v.y + v.z * v.z + v.w * v.w;
  ss = block_sum256(ss);
  float inv = rsqrtf(ss * (1.0f / E_DIM));
  float4 o;
  o.x = v.x * (1.0f + inv);
  o.y = v.y * (1.0f + inv);
  o.z = v.z * (1.0f + inv);
  o.w = v.w * (1.0f + inv);
  ((float4*)(Xout + row * E_DIM))[t] = o;
  short* h = H + row * E_DIM + (size_t)t * 4;
  h[0] = f2bf(v.x * inv);
  h[1] = f2bf(v.y * inv);
  h[2] = f2bf(v.z * inv);
  h[3] = f2bf(v.w * inv);
}

// ---- out = X2 + p0 + p1 (final residual) ----
__global__ __launch_bounds__(256) void add2_k(const float* __restrict__ X2,
                                              const float* __restrict__ P0,
                                              const float* __restrict__ P1,
                                              float* __restrict__ out) {
  size_t i = (size_t)blockIdx.x * 256 + threadIdx.x;
  float4 v = ((const float4*)X2)[i];
  float4 a = ((const float4*)P0)[i];
  float4 b = ((const float4*)P1)[i];
  v.x += a.x + b.x;
  v.y += a.y + b.y;
  v.z += a.z + b.z;
  v.w += a.w + b.w;
  ((float4*)out)[i] = v;
}

// ---- GEMM: C(MxN) = A(MxK bf16) @ Bt(NxK bf16)^T, fused epilogues ----
// epi: 0 = bf16 out (+bias), 3 = (+res) f32, 4 = f32 partial (split-K via
// blockIdx.z), 5 = gated-FFN (Bt is 64-row-interleaved [Ww|Wv]; out = FF bf16)
__global__ __launch_bounds__(256, 2) void gemm_bt(
    const short* __restrict__ A, const short* __restrict__ Bt,
    const float* __restrict__ bias, const float* __restrict__ res,
    void* __restrict__ out, int M, int N, int K, int epi, int ksplit) {
  __shared__ short smem[128 * 32 * 2];
  short* As = smem;
  short* Bs = smem + 128 * 32;
  int t = threadIdx.x;
  int lane = t & 63;
  int quad = lane >> 4, l16 = lane & 15;
  int wave = t >> 6;
  int wr = wave >> 1, wc = wave & 1;
  int m0 = blockIdx.y * 128, n0 = blockIdx.x * 128;
  int klen = K / ksplit;
  int kstart = blockIdx.z * klen;

  f32x4 acc[4][4];
#pragma unroll
  for (int i = 0; i < 4; i++)
#pragma unroll
    for (int j = 0; j < 4; j++) acc[i][j] = (f32x4){0.f, 0.f, 0.f, 0.f};

  for (int k0 = kstart; k0 < kstart + klen; k0 += 32) {
    __syncthreads();
#pragma unroll
    for (int p = 0; p < 2; p++) {
      int s = p * 256 + t;
      int mm = s >> 2, kk = (s & 3) * 8;
      async_copy16(A + (size_t)(m0 + mm) * K + k0 + kk,
                   (char*)As + (size_t)s * 16);
      async_copy16(Bt + (size_t)(n0 + mm) * K + k0 + kk,
                   (char*)Bs + (size_t)s * 16);
    }
    __syncthreads();
    short8 af[4], bfv[4];
#pragma unroll
    for (int i = 0; i < 4; i++) {
      af[i] = *(const short8*)&As[(wr * 64 + i * 16 + l16) * 32 + quad * 8];
      bfv[i] = *(const short8*)&Bs[(wc * 64 + i * 16 + l16) * 32 + quad * 8];
    }
#pragma unroll
    for (int mi = 0; mi < 4; mi++)
#pragma unroll
      for (int ni = 0; ni < 4; ni++)
        acc[mi][ni] = __builtin_amdgcn_mfma_f32_16x16x32_bf16(
            af[mi], bfv[ni], acc[mi][ni], 0, 0, 0);
  }

  if (epi == 5) {
    // gated FFN: wc==0 waves hold gelu-input, wc==1 hold gate, for the SAME
    // 64 output columns (Bcat interleaved). Exchange gelu(w) via LDS.
    __syncthreads();  // all waves done with As/Bs reads
    short* xbuf = smem;  // 128 rows x 64 cols bf16 = 16 KB
    if (wc == 0) {
#pragma unroll
      for (int mi = 0; mi < 4; mi++)
#pragma unroll
        for (int ni = 0; ni < 4; ni++)
#pragma unroll
          for (int r = 0; r < 4; r++) {
            int rowl = wr * 64 + mi * 16 + quad * 4 + r;
            float v = acc[mi][ni][r];
            float g = 0.5f * v * (1.0f + erff(v * 0.70710678118654752f));
            xbuf[rowl * 64 + ni * 16 + l16] = f2bf(g);
          }
    }
    __syncthreads();
    if (wc == 1) {
      short* FF = (short*)out;
#pragma unroll
      for (int mi = 0; mi < 4; mi++)
#pragma unroll
        for (int ni = 0; ni < 4; ni++)
#pragma unroll
          for (int r = 0; r < 4; r++) {
            int rowl = wr * 64 + mi * 16 + quad * 4 + r;
            int coll = ni * 16 + l16;
            float w = bf2f(xbuf[rowl * 64 + coll]);
            FF[(size_t)(m0 + rowl) * DFF_DIM + blockIdx.x * 64 + coll] =
                f2bf(w * acc[mi][ni][r]);
          }
    }
    return;
  }

#pragma unroll
  for (int mi = 0; mi < 4; mi++) {
#pragma unroll
    for (int ni = 0; ni < 4; ni++) {
      int col = n0 + wc * 64 + ni * 16 + l16;
      float bv = bias ? bias[col] : 0.0f;
#pragma unroll
      for (int r = 0; r < 4; r++) {
        int row = m0 + wr * 64 + mi * 16 + quad * 4 + r;
        size_t idx = (size_t)row * N + col;
        float v = acc[mi][ni][r] + bv;
        if (epi == 0) {
          ((short*)out)[idx] = f2bf(v);
        } else if (epi == 3) {
          ((float*)out)[idx] = v + res[idx];
        } else {  // epi == 4: split-K partial
          float* po = (float*)out + (size_t)blockIdx.z * ((size_t)M * N);
          po[idx] = v;
        }
      }
    }
  }
}

// ---- K/V prep: Kh[bh][l][d] copy; VTh[bh][d][l] transpose ----
__global__ __launch_bounds__(256) void kv_prep(const short* __restrict__ qkv,
                                               short* __restrict__ Kh,
                                               short* __restrict__ VTh) {
  int lt = blockIdx.x, bh = blockIdx.y;
  int b = bh >> 4, h = bh & 15;
  __shared__ short vtile[64 * 72];
  int t = threadIdx.x;
  int r = t >> 3, c = (t & 7) * 8;
  const short* base =
      qkv + (size_t)(b * L_SEQ + lt * 64) * (3 * NH * DH) + h * (3 * DH);
#pragma unroll
  for (int p = 0; p < 2; p++) {
    int row = r + p * 32;
    short8 kv = *(const short8*)(base + (size_t)row * (3 * NH * DH) + DH + c);
    *(short8*)(Kh + ((size_t)bh * L_SEQ + lt * 64 + row) * DH + c) = kv;
    short8 vv =
        *(const short8*)(base + (size_t)row * (3 * NH * DH) + 2 * DH + c);
    *(short8*)&vtile[row * 72 + c] = vv;
  }
  __syncthreads();
#pragma unroll
  for (int p = 0; p < 2; p++) {
    int d = r + p * 32;
    short8 o;
#pragma unroll
    for (int u = 0; u < 8; u++) o[u] = vtile[(c + u) * 72 + d];
    *(short8*)(VTh + ((size_t)bh * DH + d) * L_SEQ + lt * 64 + c) = o;
  }
}

// ---- flash attention, constant-m online softmax (m = 8, shift-invariant) ----
__global__ __launch_bounds__(256) void attn_k(const short* __restrict__ qkv,
                                              const short* __restrict__ Kh,
                                              const short* __restrict__ VTh,
                                              short* __restrict__ ctx) {
  int qt = (gridDim.x - 1) - blockIdx.x;  // longest blocks first
  int bh = blockIdx.y;
  int b = bh >> 4, h = bh & 15;
  int t = threadIdx.x;
  int wave = t >> 6, lane = t & 63;
  int quad = lane >> 4, l16 = lane & 15;

  __shared__ short kt[64 * 72];
  __shared__ short vt[64 * 72];
  __shared__ short pb[4 * 16 * 70];

  const float slope = exp2f(-(1.0f + (7.0f / 15.0f) * (float)h));
  const size_t rowstride = 3 * NH * DH;
  const short* qbase = qkv + (size_t)(b * L_SEQ) * rowstride + h * (3 * DH);
  int iw = qt * 64 + wave * 16;

  short8 qf[2];
  {
    const short* qp = qbase + (size_t)(iw + l16) * rowstride + quad * 8;
    qf[0] = *(const short8*)(qp);
    qf[1] = *(const short8*)(qp + 32);
  }

  f32x4 o[4];
#pragma unroll
  for (int i = 0; i < 4; i++) o[i] = (f32x4){0.f, 0.f, 0.f, 0.f};
  float rs[4] = {0.f, 0.f, 0.f, 0.f};
  float crow[4];
  int irow[4];
#pragma unroll
  for (int r = 0; r < 4; r++) {
    irow[r] = iw + quad * 4 + r;
    crow[r] = -slope * (float)irow[r] - 8.0f;
  }

  int sr = t >> 3, sc = (t & 7) * 8;
  const short* kg = Kh + (size_t)bh * L_SEQ * DH;
  const short* vg = VTh + (size_t)bh * DH * L_SEQ;
  short8 kreg[2], vreg[2];
  auto loadKV = [&](int j0) {
    kreg[0] = *(const short8*)(kg + (size_t)(j0 + sr) * DH + sc);
    kreg[1] = *(const short8*)(kg + (size_t)(j0 + sr + 32) * DH + sc);
    vreg[0] = *(const short8*)(vg + (size_t)sr * L_SEQ + j0 + sc);
    vreg[1] = *(const short8*)(vg + (size_t)(sr + 32) * L_SEQ + j0 + sc);
  };
  loadKV(0);

  short* pw = &pb[wave * 16 * 70];
  int ntile = qt + 1;
  for (int tix = 0; tix < ntile; ++tix) {
    int j0 = tix * 64;
    __syncthreads();
    *(short8*)&kt[sr * 72 + sc] = kreg[0];
    *(short8*)&kt[(sr + 32) * 72 + sc] = kreg[1];
    *(short8*)&vt[sr * 72 + sc] = vreg[0];
    *(short8*)&vt[(sr + 32) * 72 + sc] = vreg[1];
    __syncthreads();
    if (tix + 1 < ntile) loadKV(j0 + 64);

    f32x4 s[4];
#pragma unroll
    for (int nt = 0; nt < 4; nt++) {
      f32x4 a = (f32x4){0.f, 0.f, 0.f, 0.f};
#pragma unroll
      for (int ks = 0; ks < 2; ks++) {
        short8 bf =
            *(const short8*)&kt[(nt * 16 + l16) * 72 + ks * 32 + quad * 8];
        a = __builtin_amdgcn_mfma_f32_16x16x32_bf16(qf[ks], bf, a, 0, 0, 0);
      }
      s[nt] = a;
    }
    bool diag = (tix == ntile - 1);
#pragma unroll
    for (int nt = 0; nt < 4; nt++) {
      int j = j0 + nt * 16 + l16;
      float jb = slope * (float)j;
#pragma unroll
      for (int r = 0; r < 4; r++) {
        float v = __builtin_fmaf(s[nt][r], 0.125f, jb + crow[r]);
        if (diag && j > irow[r]) v = -1e30f;
        float p = __expf(v);
        rs[r] += p;
        pw[(quad * 4 + r) * 70 + nt * 16 + l16] = f2bf(p);
      }
    }
    short8 pf[2];
    pf[0] = *(const short8*)&pw[l16 * 70 + quad * 8];
    pf[1] = *(const short8*)&pw[l16 * 70 + 32 + quad * 8];
#pragma unroll
    for (int nt = 0; nt < 4; nt++) {
#pragma unroll
      for (int ks = 0; ks < 2; ks++) {
        short8 bv =
            *(const short8*)&vt[(nt * 16 + l16) * 72 + ks * 32 + quad * 8];
        o[nt] = __builtin_amdgcn_mfma_f32_16x16x32_bf16(pf[ks], bv, o[nt], 0,
                                                        0, 0);
      }
    }
  }
#pragma unroll
  for (int r = 0; r < 4; r++) {
#pragma unroll
    for (int off = 1; off < 16; off <<= 1) rs[r] += __shfl_xor(rs[r], off, 64);
    float inv = 1.0f / rs[r];
    short* dst = ctx + (size_t)(b * L_SEQ + irow[r]) * (NH * DH) + h * DH;
#pragma unroll
    for (int nt = 0; nt < 4; nt++) dst[nt * 16 + l16] = f2bf(o[nt][r] * inv);
  }
}

extern "C" void kernel_launch(void* const* d_in, const int* in_sizes, int n_in,
                              void* d_out, int out_size, void* d_ws,
                              size_t ws_size, hipStream_t stream) {
  const float* X = (const float*)d_in[0];
  const float* Wqkv = (const float*)d_in[2];
  const float* bqkv = (const float*)d_in[3];
  const float* Wo_sa = (const float*)d_in[4];
  const float* bo_sa = (const float*)d_in[5];
  const float* Ww = (const float*)d_in[12];
  const float* Wv = (const float*)d_in[13];
  const float* Wout = (const float*)d_in[14];

  char* ws = (char*)d_ws;
  auto take = [&](size_t bytes) {
    char* p = ws;
    ws += (bytes + 255) & ~(size_t)255;
    return p;
  };
  short* WqkvT = (short*)take((size_t)3 * NH * DH * E_DIM * 2);  // 6 MB
  short* WoT = (short*)take((size_t)E_DIM * E_DIM * 2);          // 2 MB
  short* Bcat = (short*)take((size_t)2 * DFF_DIM * E_DIM * 2);   // 16 MB
  short* WoutT = (short*)take((size_t)E_DIM * DFF_DIM * 2);      // 8 MB
  short* Hbuf = (short*)take((size_t)ROWS * E_DIM * 2);          // 8 MB
  short* QKV = (short*)take((size_t)ROWS * 3 * NH * DH * 2);     // 24 MB
  short* CTX = (short*)take((size_t)ROWS * NH * DH * 2);         // 8 MB
  float* X1 = (float*)take((size_t)ROWS * E_DIM * 4);            // 16 MB
  short* KVb = (short*)take((size_t)2 * B_SZ * NH * L_SEQ * DH * 2);  // 16 MB
  short* FF = (short*)take((size_t)ROWS * DFF_DIM * 2);          // 32 MB
  short* Kh = KVb;
  short* VTh = KVb + (size_t)B_SZ * NH * L_SEQ * DH;
  // split-K partial buffers (32 MB each), aliased onto dead regions:
  float* Pwo = (float*)FF;    // FF not yet written when Wo partials live
  float* Pwout = (float*)QKV; // QKV+CTX dead after attention+Wo (32 MB contig)
  (void)ws_size;
  (void)in_sizes;
  (void)n_in;
  (void)out_size;

  dim3 blk(256);
  transpose_f32_to_bf16<<<dim3(3072 / 32, 1024 / 32), blk, 0, stream>>>(
      Wqkv, WqkvT, 1024, 3072, -1);
  transpose_f32_to_bf16<<<dim3(1024 / 32, 1024 / 32), blk, 0, stream>>>(
      Wo_sa, WoT, 1024, 1024, -1);
  transpose_f32_to_bf16<<<dim3(4096 / 32, 1024 / 32), blk, 0, stream>>>(
      Ww, Bcat, 1024, 4096, 0);
  transpose_f32_to_bf16<<<dim3(4096 / 32, 1024 / 32), blk, 0, stream>>>(
      Wv, Bcat, 1024, 4096, 64);
  transpose_f32_to_bf16<<<dim3(1024 / 32, 4096 / 32), blk, 0, stream>>>(
      Wout, WoutT, 4096, 1024, -1);

  rmsnorm_k<<<ROWS, blk, 0, stream>>>(X, Hbuf);
  // qkv = h @ Wqkv + bqkv  -> bf16   (768 blocks)
  gemm_bt<<<dim3(3072 / 128, ROWS / 128), blk, 0, stream>>>(
      Hbuf, WqkvT, bqkv, nullptr, QKV, ROWS, 3072, 1024, 0, 1);
  kv_prep<<<dim3(L_SEQ / 64, B_SZ * NH), blk, 0, stream>>>(QKV, Kh, VTh);
  attn_k<<<dim3(L_SEQ / 64, B_SZ * NH), blk, 0, stream>>>(QKV, Kh, VTh, CTX);
  // Wo partials, split-K=2 (512 blocks)
  gemm_bt<<<dim3(1024 / 128, ROWS / 128, 2), blk, 0, stream>>>(
      CTX, WoT, nullptr, nullptr, Pwo, ROWS, 1024, 1024, 4, 2);
  // X1 = X + p0 + p1 + bo_sa; X2 -> X1 buf; h2 -> Hbuf
  resid_rms_fused<<<ROWS, blk, 0, stream>>>(
      X, Pwo, Pwo + (size_t)ROWS * E_DIM, bo_sa, X1, Hbuf);
  // gated FFN: FF = gelu(h2@Ww) * (h2@Wv)  (2048 blocks, fused)
  gemm_bt<<<dim3(2 * DFF_DIM / 128, ROWS / 128), blk, 0, stream>>>(
      Hbuf, Bcat, nullptr, nullptr, FF, ROWS, 2 * DFF_DIM, 1024, 5, 1);
  // Wout partials, split-K=2 (512 blocks)
  gemm_bt<<<dim3(1024 / 128, ROWS / 128, 2), blk, 0, stream>>>(
      FF, WoutT, nullptr, nullptr, Pwout, ROWS, 1024, 4096, 4, 2);
  // out = X2 + p0 + p1
  add2_k<<<ROWS * E_DIM / (256 * 4), blk, 0, stream>>>(
      X1, Pwout, Pwout + (size_t)ROWS * E_DIM, (float*)d_out);
}

// Round 4
// 470.704 us; speedup vs baseline: 1.3318x; 1.0592x over previous
//
#include <hip/hip_runtime.h>

#define B_SZ 2
#define L_SEQ 2048
#define E_DIM 1024
#define NH 16
#define DH 64
#define DFF_DIM 4096
#define ROWS (B_SZ * L_SEQ)  // 4096

typedef __attribute__((ext_vector_type(8))) short short8;
typedef __attribute__((ext_vector_type(4))) float f32x4;

// ---- bf16 <-> f32 helpers ----
__device__ __forceinline__ short f2bf(float f) {
  unsigned u = __builtin_bit_cast(unsigned, f);
  u = (u + 0x7FFFu + ((u >> 16) & 1u)) >> 16;
  return (short)u;
}
__device__ __forceinline__ float bf2f(short s) {
  unsigned u = ((unsigned)(unsigned short)s) << 16;
  return __builtin_bit_cast(float, u);
}

// ---- async global->LDS 16B copy ----
__device__ __forceinline__ void async_copy16(const void* g, void* l) {
  __builtin_amdgcn_global_load_lds(
      (const __attribute__((address_space(1))) void*)g,
      (__attribute__((address_space(3))) void*)l, 16, 0, 0);
}

// ---- block reduction over 256 threads (4 waves) ----
__device__ __forceinline__ float block_sum256(float v) {
  __shared__ float sbuf[4];
#pragma unroll
  for (int off = 32; off > 0; off >>= 1) v += __shfl_xor(v, off, 64);
  int lane = threadIdx.x & 63, w = threadIdx.x >> 6;
  if (lane == 0) sbuf[w] = v;
  __syncthreads();
  return sbuf[0] + sbuf[1] + sbuf[2] + sbuf[3];
}

// ---- fused prep: 5 weight transposes (f32 KxN -> bf16 NxK, optional
// 64-row interleave) + rmsnorm(X)->Hbuf, one launch, block-range dispatch ----
__global__ __launch_bounds__(256) void prep_all(
    const float* __restrict__ Wqkv, const float* __restrict__ Wo,
    const float* __restrict__ Ww, const float* __restrict__ Wv,
    const float* __restrict__ Wout, const float* __restrict__ X,
    short* __restrict__ WqkvT, short* __restrict__ WoT,
    short* __restrict__ Bcat, short* __restrict__ WoutT,
    short* __restrict__ H) {
  __shared__ float tile[32][33];
  int b = blockIdx.x;
  if (b < 16384) {
    const float* W;
    short* Wt;
    int K, N, poff, bx, by;
    if (b < 3072) {
      W = Wqkv; Wt = WqkvT; K = 1024; N = 3072; poff = -1;
      bx = b % 96; by = b / 96;
    } else if (b < 4096) {
      int c = b - 3072;
      W = Wo; Wt = WoT; K = 1024; N = 1024; poff = -1;
      bx = c & 31; by = c >> 5;
    } else if (b < 8192) {
      int c = b - 4096;
      W = Ww; Wt = Bcat; K = 1024; N = 4096; poff = 0;
      bx = c & 127; by = c >> 7;
    } else if (b < 12288) {
      int c = b - 8192;
      W = Wv; Wt = Bcat; K = 1024; N = 4096; poff = 64;
      bx = c & 127; by = c >> 7;
    } else {
      int c = b - 12288;
      W = Wout; Wt = WoutT; K = 4096; N = 1024; poff = -1;
      bx = c & 31; by = c >> 5;
    }
    int n0 = bx * 32, k0 = by * 32;
    int tx = threadIdx.x & 31, ty = threadIdx.x >> 5;
#pragma unroll
    for (int i = 0; i < 4; i++)
      tile[ty + 8 * i][tx] = W[(size_t)(k0 + ty + 8 * i) * N + n0 + tx];
    __syncthreads();
#pragma unroll
    for (int i = 0; i < 4; i++) {
      int n = n0 + ty + 8 * i;
      int orow = (poff < 0) ? n : ((n >> 6) * 128 + (n & 63) + poff);
      Wt[(size_t)orow * K + k0 + tx] = f2bf(tile[tx][ty + 8 * i]);
    }
  } else {
    size_t row = b - 16384;
    float4 v = ((const float4*)(X + row * E_DIM))[threadIdx.x];
    float ss = v.x * v.x + v.y * v.y + v.z * v.z + v.w * v.w;
    ss = block_sum256(ss);
    float inv = rsqrtf(ss * (1.0f / E_DIM));
    short* h = H + row * E_DIM + (size_t)threadIdx.x * 4;
    h[0] = f2bf(v.x * inv);
    h[1] = f2bf(v.y * inv);
    h[2] = f2bf(v.z * inv);
    h[3] = f2bf(v.w * inv);
  }
}

// ---- fused: X1 = X + p0 + p1 + bias; X2 = X1*(1+1/rms); h2 = X1/rms ----
__global__ __launch_bounds__(256) void resid_rms_fused(
    const float* __restrict__ X, const float* __restrict__ P0,
    const float* __restrict__ P1, const float* __restrict__ bias,
    float* __restrict__ Xout, short* __restrict__ H) {
  size_t row = blockIdx.x;
  int t = threadIdx.x;
  float4 v = ((const float4*)(X + row * E_DIM))[t];
  float4 a = ((const float4*)(P0 + row * E_DIM))[t];
  float4 b = ((const float4*)(P1 + row * E_DIM))[t];
  float4 c = ((const float4*)bias)[t];
  v.x += a.x + b.x + c.x;
  v.y += a.y + b.y + c.y;
  v.z += a.z + b.z + c.z;
  v.w += a.w + b.w + c.w;
  float ss = v.x * v.x + v.y * v.y + v.z * v.z + v.w * v.w;
  ss = block_sum256(ss);
  float inv = rsqrtf(ss * (1.0f / E_DIM));
  float4 o;
  o.x = v.x * (1.0f + inv);
  o.y = v.y * (1.0f + inv);
  o.z = v.z * (1.0f + inv);
  o.w = v.w * (1.0f + inv);
  ((float4*)(Xout + row * E_DIM))[t] = o;
  short* h = H + row * E_DIM + (size_t)t * 4;
  h[0] = f2bf(v.x * inv);
  h[1] = f2bf(v.y * inv);
  h[2] = f2bf(v.z * inv);
  h[3] = f2bf(v.w * inv);
}

// ---- out = X2 + p0 + p1 (final residual) ----
__global__ __launch_bounds__(256) void add2_k(const float* __restrict__ X2,
                                              const float* __restrict__ P0,
                                              const float* __restrict__ P1,
                                              float* __restrict__ out) {
  size_t i = (size_t)blockIdx.x * 256 + threadIdx.x;
  float4 v = ((const float4*)X2)[i];
  float4 a = ((const float4*)P0)[i];
  float4 b = ((const float4*)P1)[i];
  v.x += a.x + b.x;
  v.y += a.y + b.y;
  v.z += a.z + b.z;
  v.w += a.w + b.w;
  ((float4*)out)[i] = v;
}

// ---- GEMM: C(MxN) = A(MxK bf16) @ Bt(NxK bf16)^T, BK=64 twin buffers ----
// epi: 0 = bf16 out (+bias), 3 = (+res) f32, 4 = f32 partial (split-K via
// blockIdx.z), 5 = gated-FFN (Bt is 64-row-interleaved [Ww|Wv]; out = FF bf16)
__global__ __launch_bounds__(256, 2) void gemm_bt(
    const short* __restrict__ A, const short* __restrict__ Bt,
    const float* __restrict__ bias, const float* __restrict__ res,
    void* __restrict__ out, int M, int N, int K, int epi, int ksplit) {
  __shared__ short smem[128 * 32 * 4];  // As0 Bs0 As1 Bs1 = 32 KB
  short* As0 = smem;
  short* Bs0 = smem + 4096;
  short* As1 = smem + 8192;
  short* Bs1 = smem + 12288;
  int t = threadIdx.x;
  int lane = t & 63;
  int quad = lane >> 4, l16 = lane & 15;
  int wave = t >> 6;
  int wr = wave >> 1, wc = wave & 1;
  int m0 = blockIdx.y * 128, n0 = blockIdx.x * 128;
  int klen = K / ksplit;
  int kstart = blockIdx.z * klen;

  f32x4 acc[4][4];
#pragma unroll
  for (int i = 0; i < 4; i++)
#pragma unroll
    for (int j = 0; j < 4; j++) acc[i][j] = (f32x4){0.f, 0.f, 0.f, 0.f};

  for (int k0 = kstart; k0 < kstart + klen; k0 += 64) {
    __syncthreads();
#pragma unroll
    for (int p = 0; p < 2; p++) {
      int s = p * 256 + t;  // chunk id 0..511 (16 B chunks of a 128x32 tile)
      int mm = s >> 2, kk = (s & 3) * 8;
      const short* ag = A + (size_t)(m0 + mm) * K + k0 + kk;
      const short* bg = Bt + (size_t)(n0 + mm) * K + k0 + kk;
      async_copy16(ag, As0 + (size_t)s * 8);
      async_copy16(bg, Bs0 + (size_t)s * 8);
      async_copy16(ag + 32, As1 + (size_t)s * 8);
      async_copy16(bg + 32, Bs1 + (size_t)s * 8);
    }
    __syncthreads();
#pragma unroll
    for (int half = 0; half < 2; half++) {
      const short* As = half ? As1 : As0;
      const short* Bs = half ? Bs1 : Bs0;
      short8 af[4], bfv[4];
#pragma unroll
      for (int i = 0; i < 4; i++) {
        af[i] = *(const short8*)&As[(wr * 64 + i * 16 + l16) * 32 + quad * 8];
        bfv[i] = *(const short8*)&Bs[(wc * 64 + i * 16 + l16) * 32 + quad * 8];
      }
#pragma unroll
      for (int mi = 0; mi < 4; mi++)
#pragma unroll
        for (int ni = 0; ni < 4; ni++)
          acc[mi][ni] = __builtin_amdgcn_mfma_f32_16x16x32_bf16(
              af[mi], bfv[ni], acc[mi][ni], 0, 0, 0);
    }
  }

  if (epi == 5) {
    // gated FFN: wc==0 waves hold gelu-input, wc==1 hold gate, same 64 cols.
    __syncthreads();         // all waves done with LDS tile reads
    short* xbuf = smem;      // 128 rows x 64 cols, stride 68 (bank-spread)
    if (wc == 0) {
#pragma unroll
      for (int mi = 0; mi < 4; mi++)
#pragma unroll
        for (int ni = 0; ni < 4; ni++)
#pragma unroll
          for (int r = 0; r < 4; r++) {
            int rowl = wr * 64 + mi * 16 + quad * 4 + r;
            float v = acc[mi][ni][r];
            float g = 0.5f * v * (1.0f + erff(v * 0.70710678118654752f));
            xbuf[rowl * 68 + ni * 16 + l16] = f2bf(g);
          }
    }
    __syncthreads();
    if (wc == 1) {
      short* FF = (short*)out;
#pragma unroll
      for (int mi = 0; mi < 4; mi++)
#pragma unroll
        for (int ni = 0; ni < 4; ni++)
#pragma unroll
          for (int r = 0; r < 4; r++) {
            int rowl = wr * 64 + mi * 16 + quad * 4 + r;
            int coll = ni * 16 + l16;
            float w = bf2f(xbuf[rowl * 68 + coll]);
            FF[(size_t)(m0 + rowl) * DFF_DIM + blockIdx.x * 64 + coll] =
                f2bf(w * acc[mi][ni][r]);
          }
    }
    return;
  }

#pragma unroll
  for (int mi = 0; mi < 4; mi++) {
#pragma unroll
    for (int ni = 0; ni < 4; ni++) {
      int col = n0 + wc * 64 + ni * 16 + l16;
      float bv = bias ? bias[col] : 0.0f;
#pragma unroll
      for (int r = 0; r < 4; r++) {
        int row = m0 + wr * 64 + mi * 16 + quad * 4 + r;
        size_t idx = (size_t)row * N + col;
        float v = acc[mi][ni][r] + bv;
        if (epi == 0) {
          ((short*)out)[idx] = f2bf(v);
        } else if (epi == 3) {
          ((float*)out)[idx] = v + res[idx];
        } else {  // epi == 4: split-K partial
          float* po = (float*)out + (size_t)blockIdx.z * ((size_t)M * N);
          po[idx] = v;
        }
      }
    }
  }
}

// ---- K/V prep: Kh[bh][l][d] copy; VTh[bh][d][l] transpose ----
__global__ __launch_bounds__(256) void kv_prep(const short* __restrict__ qkv,
                                               short* __restrict__ Kh,
                                               short* __restrict__ VTh) {
  int lt = blockIdx.x, bh = blockIdx.y;
  int b = bh >> 4, h = bh & 15;
  __shared__ short vtile[64 * 72];
  int t = threadIdx.x;
  int r = t >> 3, c = (t & 7) * 8;
  const short* base =
      qkv + (size_t)(b * L_SEQ + lt * 64) * (3 * NH * DH) + h * (3 * DH);
#pragma unroll
  for (int p = 0; p < 2; p++) {
    int row = r + p * 32;
    short8 kv = *(const short8*)(base + (size_t)row * (3 * NH * DH) + DH + c);
    *(short8*)(Kh + ((size_t)bh * L_SEQ + lt * 64 + row) * DH + c) = kv;
    short8 vv =
        *(const short8*)(base + (size_t)row * (3 * NH * DH) + 2 * DH + c);
    *(short8*)&vtile[row * 72 + c] = vv;
  }
  __syncthreads();
#pragma unroll
  for (int p = 0; p < 2; p++) {
    int d = r + p * 32;
    short8 o;
#pragma unroll
    for (int u = 0; u < 8; u++) o[u] = vtile[(c + u) * 72 + d];
    *(short8*)(VTh + ((size_t)bh * DH + d) * L_SEQ + lt * 64 + c) = o;
  }
}

// ---- flash attention, constant-m online softmax (m = 8, shift-invariant) ----
__global__ __launch_bounds__(256) void attn_k(const short* __restrict__ qkv,
                                              const short* __restrict__ Kh,
                                              const short* __restrict__ VTh,
                                              short* __restrict__ ctx) {
  int qt = (gridDim.x - 1) - blockIdx.x;  // longest blocks first
  int bh = blockIdx.y;
  int b = bh >> 4, h = bh & 15;
  int t = threadIdx.x;
  int wave = t >> 6, lane = t & 63;
  int quad = lane >> 4, l16 = lane & 15;

  __shared__ short kt[64 * 72];
  __shared__ short vt[64 * 72];
  __shared__ short pb[4 * 16 * 70];

  const float slope = exp2f(-(1.0f + (7.0f / 15.0f) * (float)h));
  const size_t rowstride = 3 * NH * DH;
  const short* qbase = qkv + (size_t)(b * L_SEQ) * rowstride + h * (3 * DH);
  int iw = qt * 64 + wave * 16;

  short8 qf[2];
  {
    const short* qp = qbase + (size_t)(iw + l16) * rowstride + quad * 8;
    qf[0] = *(const short8*)(qp);
    qf[1] = *(const short8*)(qp + 32);
  }

  f32x4 o[4];
#pragma unroll
  for (int i = 0; i < 4; i++) o[i] = (f32x4){0.f, 0.f, 0.f, 0.f};
  float rs[4] = {0.f, 0.f, 0.f, 0.f};
  float crow[4];
  int irow[4];
#pragma unroll
  for (int r = 0; r < 4; r++) {
    irow[r] = iw + quad * 4 + r;
    crow[r] = -slope * (float)irow[r] - 8.0f;
  }

  int sr = t >> 3, sc = (t & 7) * 8;
  const short* kg = Kh + (size_t)bh * L_SEQ * DH;
  const short* vg = VTh + (size_t)bh * DH * L_SEQ;
  short8 kreg[2], vreg[2];
  auto loadKV = [&](int j0) {
    kreg[0] = *(const short8*)(kg + (size_t)(j0 + sr) * DH + sc);
    kreg[1] = *(const short8*)(kg + (size_t)(j0 + sr + 32) * DH + sc);
    vreg[0] = *(const short8*)(vg + (size_t)sr * L_SEQ + j0 + sc);
    vreg[1] = *(const short8*)(vg + (size_t)(sr + 32) * L_SEQ + j0 + sc);
  };
  loadKV(0);

  short* pw = &pb[wave * 16 * 70];
  int ntile = qt + 1;
  for (int tix = 0; tix < ntile; ++tix) {
    int j0 = tix * 64;
    __syncthreads();
    *(short8*)&kt[sr * 72 + sc] = kreg[0];
    *(short8*)&kt[(sr + 32) * 72 + sc] = kreg[1];
    *(short8*)&vt[sr * 72 + sc] = vreg[0];
    *(short8*)&vt[(sr + 32) * 72 + sc] = vreg[1];
    __syncthreads();
    if (tix + 1 < ntile) loadKV(j0 + 64);

    f32x4 s[4];
#pragma unroll
    for (int nt = 0; nt < 4; nt++) {
      f32x4 a = (f32x4){0.f, 0.f, 0.f, 0.f};
#pragma unroll
      for (int ks = 0; ks < 2; ks++) {
        short8 bf =
            *(const short8*)&kt[(nt * 16 + l16) * 72 + ks * 32 + quad * 8];
        a = __builtin_amdgcn_mfma_f32_16x16x32_bf16(qf[ks], bf, a, 0, 0, 0);
      }
      s[nt] = a;
    }
    bool diag = (tix == ntile - 1);
#pragma unroll
    for (int nt = 0; nt < 4; nt++) {
      int j = j0 + nt * 16 + l16;
      float jb = slope * (float)j;
#pragma unroll
      for (int r = 0; r < 4; r++) {
        float v = __builtin_fmaf(s[nt][r], 0.125f, jb + crow[r]);
        if (diag && j > irow[r]) v = -1e30f;
        float p = __expf(v);
        rs[r] += p;
        pw[(quad * 4 + r) * 70 + nt * 16 + l16] = f2bf(p);
      }
    }
    short8 pf[2];
    pf[0] = *(const short8*)&pw[l16 * 70 + quad * 8];
    pf[1] = *(const short8*)&pw[l16 * 70 + 32 + quad * 8];
#pragma unroll
    for (int nt = 0; nt < 4; nt++) {
#pragma unroll
      for (int ks = 0; ks < 2; ks++) {
        short8 bv =
            *(const short8*)&vt[(nt * 16 + l16) * 72 + ks * 32 + quad * 8];
        o[nt] = __builtin_amdgcn_mfma_f32_16x16x32_bf16(pf[ks], bv, o[nt], 0,
                                                        0, 0);
      }
    }
  }
#pragma unroll
  for (int r = 0; r < 4; r++) {
#pragma unroll
    for (int off = 1; off < 16; off <<= 1) rs[r] += __shfl_xor(rs[r], off, 64);
    float inv = 1.0f / rs[r];
    short* dst = ctx + (size_t)(b * L_SEQ + irow[r]) * (NH * DH) + h * DH;
#pragma unroll
    for (int nt = 0; nt < 4; nt++) dst[nt * 16 + l16] = f2bf(o[nt][r] * inv);
  }
}

extern "C" void kernel_launch(void* const* d_in, const int* in_sizes, int n_in,
                              void* d_out, int out_size, void* d_ws,
                              size_t ws_size, hipStream_t stream) {
  const float* X = (const float*)d_in[0];
  const float* Wqkv = (const float*)d_in[2];
  const float* bqkv = (const float*)d_in[3];
  const float* Wo_sa = (const float*)d_in[4];
  const float* bo_sa = (const float*)d_in[5];
  const float* Ww = (const float*)d_in[12];
  const float* Wv = (const float*)d_in[13];
  const float* Wout = (const float*)d_in[14];

  char* ws = (char*)d_ws;
  auto take = [&](size_t bytes) {
    char* p = ws;
    ws += (bytes + 255) & ~(size_t)255;
    return p;
  };
  short* WqkvT = (short*)take((size_t)3 * NH * DH * E_DIM * 2);  // 6 MB
  short* WoT = (short*)take((size_t)E_DIM * E_DIM * 2);          // 2 MB
  short* Bcat = (short*)take((size_t)2 * DFF_DIM * E_DIM * 2);   // 16 MB
  short* WoutT = (short*)take((size_t)E_DIM * DFF_DIM * 2);      // 8 MB
  short* Hbuf = (short*)take((size_t)ROWS * E_DIM * 2);          // 8 MB
  short* QKV = (short*)take((size_t)ROWS * 3 * NH * DH * 2);     // 24 MB
  short* CTX = (short*)take((size_t)ROWS * NH * DH * 2);         // 8 MB
  float* X1 = (float*)take((size_t)ROWS * E_DIM * 4);            // 16 MB
  short* KVb = (short*)take((size_t)2 * B_SZ * NH * L_SEQ * DH * 2);  // 16 MB
  short* FF = (short*)take((size_t)ROWS * DFF_DIM * 2);          // 32 MB
  short* Kh = KVb;
  short* VTh = KVb + (size_t)B_SZ * NH * L_SEQ * DH;
  // split-K partial buffers (32 MB each), aliased onto dead regions:
  float* Pwo = (float*)FF;     // FF not yet written when Wo partials live
  float* Pwout = (float*)QKV;  // QKV+CTX dead after attention+Wo (32 MB)
  (void)ws_size;
  (void)in_sizes;
  (void)n_in;
  (void)out_size;

  dim3 blk(256);
  // fused: 5 weight transposes + rmsnorm(X) (16384 + 4096 blocks)
  prep_all<<<16384 + ROWS, blk, 0, stream>>>(Wqkv, Wo_sa, Ww, Wv, Wout, X,
                                             WqkvT, WoT, Bcat, WoutT, Hbuf);
  // qkv = h @ Wqkv + bqkv  -> bf16   (768 blocks)
  gemm_bt<<<dim3(3072 / 128, ROWS / 128), blk, 0, stream>>>(
      Hbuf, WqkvT, bqkv, nullptr, QKV, ROWS, 3072, 1024, 0, 1);
  kv_prep<<<dim3(L_SEQ / 64, B_SZ * NH), blk, 0, stream>>>(QKV, Kh, VTh);
  attn_k<<<dim3(L_SEQ / 64, B_SZ * NH), blk, 0, stream>>>(QKV, Kh, VTh, CTX);
  // Wo partials, split-K=2 (512 blocks)
  gemm_bt<<<dim3(1024 / 128, ROWS / 128, 2), blk, 0, stream>>>(
      CTX, WoT, nullptr, nullptr, Pwo, ROWS, 1024, 1024, 4, 2);
  // X1 = X + p0 + p1 + bo_sa; X2 -> X1 buf; h2 -> Hbuf
  resid_rms_fused<<<ROWS, blk, 0, stream>>>(
      X, Pwo, Pwo + (size_t)ROWS * E_DIM, bo_sa, X1, Hbuf);
  // gated FFN: FF = gelu(h2@Ww) * (h2@Wv)  (2048 blocks, fused)
  gemm_bt<<<dim3(2 * DFF_DIM / 128, ROWS / 128), blk, 0, stream>>>(
      Hbuf, Bcat, nullptr, nullptr, FF, ROWS, 2 * DFF_DIM, 1024, 5, 1);
  // Wout partials, split-K=2 (512 blocks)
  gemm_bt<<<dim3(1024 / 128, ROWS / 128, 2), blk, 0, stream>>>(
      FF, WoutT, nullptr, nullptr, Pwout, ROWS, 1024, 4096, 4, 2);
  // out = X2 + p0 + p1
  add2_k<<<ROWS * E_DIM / (256 * 4), blk, 0, stream>>>(
      X1, Pwout, Pwout + (size_t)ROWS * E_DIM, (float*)d_out);
}

// Round 5
// 441.753 us; speedup vs baseline: 1.4190x; 1.0655x over previous
//
#include <hip/hip_runtime.h>

#define B_SZ 2
#define L_SEQ 2048
#define E_DIM 1024
#define NH 16
#define DH 64
#define DFF_DIM 4096
#define ROWS (B_SZ * L_SEQ)  // 4096
#define NCID 80              // KV chunks per (b,h): sum ceil((qt+1)/8), qt<32

typedef __attribute__((ext_vector_type(8))) short short8;
typedef __attribute__((ext_vector_type(4))) float f32x4;

// ---- bf16 <-> f32 helpers ----
__device__ __forceinline__ short f2bf(float f) {
  unsigned u = __builtin_bit_cast(unsigned, f);
  u = (u + 0x7FFFu + ((u >> 16) & 1u)) >> 16;
  return (short)u;
}
__device__ __forceinline__ float bf2f(short s) {
  unsigned u = ((unsigned)(unsigned short)s) << 16;
  return __builtin_bit_cast(float, u);
}

// ---- async global->LDS 16B copy ----
__device__ __forceinline__ void async_copy16(const void* g, void* l) {
  __builtin_amdgcn_global_load_lds(
      (const __attribute__((address_space(1))) void*)g,
      (__attribute__((address_space(3))) void*)l, 16, 0, 0);
}

// ---- block reduction over 256 threads (4 waves) ----
__device__ __forceinline__ float block_sum256(float v) {
  __shared__ float sbuf[4];
#pragma unroll
  for (int off = 32; off > 0; off >>= 1) v += __shfl_xor(v, off, 64);
  int lane = threadIdx.x & 63, w = threadIdx.x >> 6;
  if (lane == 0) sbuf[w] = v;
  __syncthreads();
  return sbuf[0] + sbuf[1] + sbuf[2] + sbuf[3];
}

// ---- fused prep: 5 weight transposes + rmsnorm(X) ----
__global__ __launch_bounds__(256) void prep_all(
    const float* __restrict__ Wqkv, const float* __restrict__ Wo,
    const float* __restrict__ Ww, const float* __restrict__ Wv,
    const float* __restrict__ Wout, const float* __restrict__ X,
    short* __restrict__ WqkvT, short* __restrict__ WoT,
    short* __restrict__ Bcat, short* __restrict__ WoutT,
    short* __restrict__ H) {
  __shared__ float tile[32][33];
  int b = blockIdx.x;
  if (b < 16384) {
    const float* W;
    short* Wt;
    int K, N, poff, bx, by;
    if (b < 3072) {
      W = Wqkv; Wt = WqkvT; K = 1024; N = 3072; poff = -1;
      bx = b % 96; by = b / 96;
    } else if (b < 4096) {
      int c = b - 3072;
      W = Wo; Wt = WoT; K = 1024; N = 1024; poff = -1;
      bx = c & 31; by = c >> 5;
    } else if (b < 8192) {
      int c = b - 4096;
      W = Ww; Wt = Bcat; K = 1024; N = 4096; poff = 0;
      bx = c & 127; by = c >> 7;
    } else if (b < 12288) {
      int c = b - 8192;
      W = Wv; Wt = Bcat; K = 1024; N = 4096; poff = 64;
      bx = c & 127; by = c >> 7;
    } else {
      int c = b - 12288;
      W = Wout; Wt = WoutT; K = 4096; N = 1024; poff = -1;
      bx = c & 31; by = c >> 5;
    }
    int n0 = bx * 32, k0 = by * 32;
    int tx = threadIdx.x & 31, ty = threadIdx.x >> 5;
#pragma unroll
    for (int i = 0; i < 4; i++)
      tile[ty + 8 * i][tx] = W[(size_t)(k0 + ty + 8 * i) * N + n0 + tx];
    __syncthreads();
#pragma unroll
    for (int i = 0; i < 4; i++) {
      int n = n0 + ty + 8 * i;
      int orow = (poff < 0) ? n : ((n >> 6) * 128 + (n & 63) + poff);
      Wt[(size_t)orow * K + k0 + tx] = f2bf(tile[tx][ty + 8 * i]);
    }
  } else {
    size_t row = b - 16384;
    float4 v = ((const float4*)(X + row * E_DIM))[threadIdx.x];
    float ss = v.x * v.x + v.y * v.y + v.z * v.z + v.w * v.w;
    ss = block_sum256(ss);
    float inv = rsqrtf(ss * (1.0f / E_DIM));
    short* h = H + row * E_DIM + (size_t)threadIdx.x * 4;
    h[0] = f2bf(v.x * inv);
    h[1] = f2bf(v.y * inv);
    h[2] = f2bf(v.z * inv);
    h[3] = f2bf(v.w * inv);
  }
}

// ---- fused: X1 = X + p0 + p1 + bias; X2 = X1*(1+1/rms); h2 = X1/rms ----
__global__ __launch_bounds__(256) void resid_rms_fused(
    const float* __restrict__ X, const float* __restrict__ P0,
    const float* __restrict__ P1, const float* __restrict__ bias,
    float* __restrict__ Xout, short* __restrict__ H) {
  size_t row = blockIdx.x;
  int t = threadIdx.x;
  float4 v = ((const float4*)(X + row * E_DIM))[t];
  float4 a = ((const float4*)(P0 + row * E_DIM))[t];
  float4 b = ((const float4*)(P1 + row * E_DIM))[t];
  float4 c = ((const float4*)bias)[t];
  v.x += a.x + b.x + c.x;
  v.y += a.y + b.y + c.y;
  v.z += a.z + b.z + c.z;
  v.w += a.w + b.w + c.w;
  float ss = v.x * v.x + v.y * v.y + v.z * v.z + v.w * v.w;
  ss = block_sum256(ss);
  float inv = rsqrtf(ss * (1.0f / E_DIM));
  float4 o;
  o.x = v.x * (1.0f + inv);
  o.y = v.y * (1.0f + inv);
  o.z = v.z * (1.0f + inv);
  o.w = v.w * (1.0f + inv);
  ((float4*)(Xout + row * E_DIM))[t] = o;
  short* h = H + row * E_DIM + (size_t)t * 4;
  h[0] = f2bf(v.x * inv);
  h[1] = f2bf(v.y * inv);
  h[2] = f2bf(v.z * inv);
  h[3] = f2bf(v.w * inv);
}

// ---- out = X2 + p0 + p1 (final residual) ----
__global__ __launch_bounds__(256) void add2_k(const float* __restrict__ X2,
                                              const float* __restrict__ P0,
                                              const float* __restrict__ P1,
                                              float* __restrict__ out) {
  size_t i = (size_t)blockIdx.x * 256 + threadIdx.x;
  float4 v = ((const float4*)X2)[i];
  float4 a = ((const float4*)P0)[i];
  float4 b = ((const float4*)P1)[i];
  v.x += a.x + b.x;
  v.y += a.y + b.y;
  v.z += a.z + b.z;
  v.w += a.w + b.w;
  ((float4*)out)[i] = v;
}

// ---- GEMM: C(MxN) = A(MxK bf16) @ Bt(NxK bf16)^T, BK=64 twin buffers ----
// epi: 0 = bf16 out (+bias), 3 = (+res) f32, 4 = f32 partial (split-K via
// blockIdx.z), 5 = gated-FFN (Bt is 64-row-interleaved [Ww|Wv]; out = FF bf16)
__global__ __launch_bounds__(256, 2) void gemm_bt(
    const short* __restrict__ A, const short* __restrict__ Bt,
    const float* __restrict__ bias, const float* __restrict__ res,
    void* __restrict__ out, int M, int N, int K, int epi, int ksplit) {
  __shared__ short smem[128 * 32 * 4];  // As0 Bs0 As1 Bs1 = 32 KB
  short* As0 = smem;
  short* Bs0 = smem + 4096;
  short* As1 = smem + 8192;
  short* Bs1 = smem + 12288;
  int t = threadIdx.x;
  int lane = t & 63;
  int quad = lane >> 4, l16 = lane & 15;
  int wave = t >> 6;
  int wr = wave >> 1, wc = wave & 1;
  int m0 = blockIdx.y * 128, n0 = blockIdx.x * 128;
  int klen = K / ksplit;
  int kstart = blockIdx.z * klen;

  f32x4 acc[4][4];
#pragma unroll
  for (int i = 0; i < 4; i++)
#pragma unroll
    for (int j = 0; j < 4; j++) acc[i][j] = (f32x4){0.f, 0.f, 0.f, 0.f};

  for (int k0 = kstart; k0 < kstart + klen; k0 += 64) {
    __syncthreads();
#pragma unroll
    for (int p = 0; p < 2; p++) {
      int s = p * 256 + t;
      int mm = s >> 2, kk = (s & 3) * 8;
      const short* ag = A + (size_t)(m0 + mm) * K + k0 + kk;
      const short* bg = Bt + (size_t)(n0 + mm) * K + k0 + kk;
      async_copy16(ag, As0 + (size_t)s * 8);
      async_copy16(bg, Bs0 + (size_t)s * 8);
      async_copy16(ag + 32, As1 + (size_t)s * 8);
      async_copy16(bg + 32, Bs1 + (size_t)s * 8);
    }
    __syncthreads();
#pragma unroll
    for (int half = 0; half < 2; half++) {
      const short* As = half ? As1 : As0;
      const short* Bs = half ? Bs1 : Bs0;
      short8 af[4], bfv[4];
#pragma unroll
      for (int i = 0; i < 4; i++) {
        af[i] = *(const short8*)&As[(wr * 64 + i * 16 + l16) * 32 + quad * 8];
        bfv[i] = *(const short8*)&Bs[(wc * 64 + i * 16 + l16) * 32 + quad * 8];
      }
#pragma unroll
      for (int mi = 0; mi < 4; mi++)
#pragma unroll
        for (int ni = 0; ni < 4; ni++)
          acc[mi][ni] = __builtin_amdgcn_mfma_f32_16x16x32_bf16(
              af[mi], bfv[ni], acc[mi][ni], 0, 0, 0);
    }
  }

  if (epi == 5) {
    __syncthreads();
    short* xbuf = smem;  // 128 rows x 64 cols, stride 68
    if (wc == 0) {
#pragma unroll
      for (int mi = 0; mi < 4; mi++)
#pragma unroll
        for (int ni = 0; ni < 4; ni++)
#pragma unroll
          for (int r = 0; r < 4; r++) {
            int rowl = wr * 64 + mi * 16 + quad * 4 + r;
            float v = acc[mi][ni][r];
            float g = 0.5f * v * (1.0f + erff(v * 0.70710678118654752f));
            xbuf[rowl * 68 + ni * 16 + l16] = f2bf(g);
          }
    }
    __syncthreads();
    if (wc == 1) {
      short* FF = (short*)out;
#pragma unroll
      for (int mi = 0; mi < 4; mi++)
#pragma unroll
        for (int ni = 0; ni < 4; ni++)
#pragma unroll
          for (int r = 0; r < 4; r++) {
            int rowl = wr * 64 + mi * 16 + quad * 4 + r;
            int coll = ni * 16 + l16;
            float w = bf2f(xbuf[rowl * 68 + coll]);
            FF[(size_t)(m0 + rowl) * DFF_DIM + blockIdx.x * 64 + coll] =
                f2bf(w * acc[mi][ni][r]);
          }
    }
    return;
  }

#pragma unroll
  for (int mi = 0; mi < 4; mi++) {
#pragma unroll
    for (int ni = 0; ni < 4; ni++) {
      int col = n0 + wc * 64 + ni * 16 + l16;
      float bv = bias ? bias[col] : 0.0f;
#pragma unroll
      for (int r = 0; r < 4; r++) {
        int row = m0 + wr * 64 + mi * 16 + quad * 4 + r;
        size_t idx = (size_t)row * N + col;
        float v = acc[mi][ni][r] + bv;
        if (epi == 0) {
          ((short*)out)[idx] = f2bf(v);
        } else if (epi == 3) {
          ((float*)out)[idx] = v + res[idx];
        } else {  // epi == 4
          float* po = (float*)out + (size_t)blockIdx.z * ((size_t)M * N);
          po[idx] = v;
        }
      }
    }
  }
}

// ---- K/V prep: Kh[bh][l][d] copy; VTh[bh][d][l] transpose ----
__global__ __launch_bounds__(256) void kv_prep(const short* __restrict__ qkv,
                                               short* __restrict__ Kh,
                                               short* __restrict__ VTh) {
  int lt = blockIdx.x, bh = blockIdx.y;
  int b = bh >> 4, h = bh & 15;
  __shared__ short vtile[64 * 72];
  int t = threadIdx.x;
  int r = t >> 3, c = (t & 7) * 8;
  const short* base =
      qkv + (size_t)(b * L_SEQ + lt * 64) * (3 * NH * DH) + h * (3 * DH);
#pragma unroll
  for (int p = 0; p < 2; p++) {
    int row = r + p * 32;
    short8 kv = *(const short8*)(base + (size_t)row * (3 * NH * DH) + DH + c);
    *(short8*)(Kh + ((size_t)bh * L_SEQ + lt * 64 + row) * DH + c) = kv;
    short8 vv =
        *(const short8*)(base + (size_t)row * (3 * NH * DH) + 2 * DH + c);
    *(short8*)&vtile[row * 72 + c] = vv;
  }
  __syncthreads();
#pragma unroll
  for (int p = 0; p < 2; p++) {
    int d = r + p * 32;
    short8 o;
#pragma unroll
    for (int u = 0; u < 8; u++) o[u] = vtile[(c + u) * 72 + d];
    *(short8*)(VTh + ((size_t)bh * DH + d) * L_SEQ + lt * 64 + c) = o;
  }
}

// ---- flash attention, constant-m softmax, split-KV (8-tile chunks) ----
// writes un-normalized O (f32) + row-sums per chunk; merged by attn_merge
__global__ __launch_bounds__(256) void attn_k(const short* __restrict__ qkv,
                                              const short* __restrict__ Kh,
                                              const short* __restrict__ VTh,
                                              float* __restrict__ OP,
                                              float* __restrict__ RS) {
  int cid = blockIdx.x;  // 0..79 flat (qt, chunk) id
  int bh = blockIdx.y;
  int b = bh >> 4, h = bh & 15;
  int qt, ch;
  if (cid < 8) {
    qt = cid; ch = 0;
  } else if (cid < 24) {
    qt = 8 + ((cid - 8) >> 1); ch = (cid - 8) & 1;
  } else if (cid < 48) {
    qt = 16 + (cid - 24) / 3; ch = (cid - 24) % 3;
  } else {
    qt = 24 + ((cid - 48) >> 2); ch = (cid - 48) & 3;
  }
  int t0 = ch * 8;
  int tend = min(t0 + 8, qt + 1);

  int t = threadIdx.x;
  int wave = t >> 6, lane = t & 63;
  int quad = lane >> 4, l16 = lane & 15;

  __shared__ short kt[64 * 72];
  __shared__ short vt[64 * 72];
  __shared__ short pb[4 * 16 * 70];

  const float slope = exp2f(-(1.0f + (7.0f / 15.0f) * (float)h));
  const size_t rowstride = 3 * NH * DH;
  const short* qbase = qkv + (size_t)(b * L_SEQ) * rowstride + h * (3 * DH);
  int iw = qt * 64 + wave * 16;

  short8 qf[2];
  {
    const short* qp = qbase + (size_t)(iw + l16) * rowstride + quad * 8;
    qf[0] = *(const short8*)(qp);
    qf[1] = *(const short8*)(qp + 32);
  }

  f32x4 o[4];
#pragma unroll
  for (int i = 0; i < 4; i++) o[i] = (f32x4){0.f, 0.f, 0.f, 0.f};
  float rs[4] = {0.f, 0.f, 0.f, 0.f};
  float crow[4];
  int irow[4];
#pragma unroll
  for (int r = 0; r < 4; r++) {
    irow[r] = iw + quad * 4 + r;
    crow[r] = -slope * (float)irow[r] - 8.0f;
  }

  int sr = t >> 3, sc = (t & 7) * 8;
  const short* kg = Kh + (size_t)bh * L_SEQ * DH;
  const short* vg = VTh + (size_t)bh * DH * L_SEQ;
  short8 kreg[2], vreg[2];
  auto loadKV = [&](int j0) {
    kreg[0] = *(const short8*)(kg + (size_t)(j0 + sr) * DH + sc);
    kreg[1] = *(const short8*)(kg + (size_t)(j0 + sr + 32) * DH + sc);
    vreg[0] = *(const short8*)(vg + (size_t)sr * L_SEQ + j0 + sc);
    vreg[1] = *(const short8*)(vg + (size_t)(sr + 32) * L_SEQ + j0 + sc);
  };
  loadKV(t0 * 64);

  short* pw = &pb[wave * 16 * 70];
  for (int tix = t0; tix < tend; ++tix) {
    int j0 = tix * 64;
    __syncthreads();
    *(short8*)&kt[sr * 72 + sc] = kreg[0];
    *(short8*)&kt[(sr + 32) * 72 + sc] = kreg[1];
    *(short8*)&vt[sr * 72 + sc] = vreg[0];
    *(short8*)&vt[(sr + 32) * 72 + sc] = vreg[1];
    __syncthreads();
    if (tix + 1 < tend) loadKV(j0 + 64);

    f32x4 s[4];
#pragma unroll
    for (int nt = 0; nt < 4; nt++) {
      f32x4 a = (f32x4){0.f, 0.f, 0.f, 0.f};
#pragma unroll
      for (int ks = 0; ks < 2; ks++) {
        short8 bf =
            *(const short8*)&kt[(nt * 16 + l16) * 72 + ks * 32 + quad * 8];
        a = __builtin_amdgcn_mfma_f32_16x16x32_bf16(qf[ks], bf, a, 0, 0, 0);
      }
      s[nt] = a;
    }
    bool diag = (tix == qt);
#pragma unroll
    for (int nt = 0; nt < 4; nt++) {
      int j = j0 + nt * 16 + l16;
      float jb = slope * (float)j;
#pragma unroll
      for (int r = 0; r < 4; r++) {
        float v = __builtin_fmaf(s[nt][r], 0.125f, jb + crow[r]);
        if (diag && j > irow[r]) v = -1e30f;
        float p = __expf(v);
        rs[r] += p;
        pw[(quad * 4 + r) * 70 + nt * 16 + l16] = f2bf(p);
      }
    }
    short8 pf[2];
    pf[0] = *(const short8*)&pw[l16 * 70 + quad * 8];
    pf[1] = *(const short8*)&pw[l16 * 70 + 32 + quad * 8];
#pragma unroll
    for (int nt = 0; nt < 4; nt++) {
#pragma unroll
      for (int ks = 0; ks < 2; ks++) {
        short8 bv =
            *(const short8*)&vt[(nt * 16 + l16) * 72 + ks * 32 + quad * 8];
        o[nt] = __builtin_amdgcn_mfma_f32_16x16x32_bf16(pf[ks], bv, o[nt], 0,
                                                        0, 0);
      }
    }
  }
  // epilogue: partial row-sum (16 j-lanes) + un-normalized O -> OP/RS
  float* op = OP + ((size_t)bh * NCID + cid) * 64 * 64;
  float* rsp = RS + ((size_t)bh * NCID + cid) * 64;
#pragma unroll
  for (int r = 0; r < 4; r++) {
#pragma unroll
    for (int off = 1; off < 16; off <<= 1) rs[r] += __shfl_xor(rs[r], off, 64);
    int rowl = wave * 16 + quad * 4 + r;
#pragma unroll
    for (int nt = 0; nt < 4; nt++) op[rowl * 64 + nt * 16 + l16] = o[nt][r];
    if (l16 == 0) rsp[rowl] = rs[r];
  }
}

// ---- merge split-KV partials: ctx = sum(O) / sum(l) -> bf16 ----
__global__ __launch_bounds__(256) void attn_merge(const float* __restrict__ OP,
                                                  const float* __restrict__ RS,
                                                  short* __restrict__ ctx) {
  int row = blockIdx.x;  // global row 0..4095
  int b = row >> 11, i = row & 2047;
  int qt = i >> 6, rowin = i & 63;
  int base, nch;
  if (qt < 8) {
    base = qt; nch = 1;
  } else if (qt < 16) {
    base = 8 + 2 * (qt - 8); nch = 2;
  } else if (qt < 24) {
    base = 24 + 3 * (qt - 16); nch = 3;
  } else {
    base = 48 + 4 * (qt - 24); nch = 4;
  }
  int t = threadIdx.x;
  int col = t * 4;
  int h = col >> 6;
  int bh = b * NH + h;
  float4 o = {0.f, 0.f, 0.f, 0.f};
  float l = 0.f;
  for (int s = 0; s < nch; s++) {
    size_t cb = ((size_t)bh * NCID + base + s) * 64 + rowin;
    float4 v = *(const float4*)&OP[cb * 64 + (col & 63)];
    o.x += v.x;
    o.y += v.y;
    o.z += v.z;
    o.w += v.w;
    l += RS[cb];
  }
  float inv = 1.0f / l;
  short* dst = ctx + (size_t)row * (NH * DH) + col;
  dst[0] = f2bf(o.x * inv);
  dst[1] = f2bf(o.y * inv);
  dst[2] = f2bf(o.z * inv);
  dst[3] = f2bf(o.w * inv);
}

extern "C" void kernel_launch(void* const* d_in, const int* in_sizes, int n_in,
                              void* d_out, int out_size, void* d_ws,
                              size_t ws_size, hipStream_t stream) {
  const float* X = (const float*)d_in[0];
  const float* Wqkv = (const float*)d_in[2];
  const float* bqkv = (const float*)d_in[3];
  const float* Wo_sa = (const float*)d_in[4];
  const float* bo_sa = (const float*)d_in[5];
  const float* Ww = (const float*)d_in[12];
  const float* Wv = (const float*)d_in[13];
  const float* Wout = (const float*)d_in[14];

  char* ws = (char*)d_ws;
  auto take = [&](size_t bytes) {
    char* p = ws;
    ws += (bytes + 255) & ~(size_t)255;
    return p;
  };
  short* WqkvT = (short*)take((size_t)3 * NH * DH * E_DIM * 2);  // 6 MB
  short* WoT = (short*)take((size_t)E_DIM * E_DIM * 2);          // 2 MB
  short* Bcat = (short*)take((size_t)2 * DFF_DIM * E_DIM * 2);   // 16 MB
  short* WoutT = (short*)take((size_t)E_DIM * DFF_DIM * 2);      // 8 MB
  short* Hbuf = (short*)take((size_t)ROWS * E_DIM * 2);          // 8 MB
  short* QKV = (short*)take((size_t)ROWS * 3 * NH * DH * 2);     // 24 MB
  short* CTX = (short*)take((size_t)ROWS * NH * DH * 2);         // 8 MB
  short* KVb = (short*)take((size_t)2 * B_SZ * NH * L_SEQ * DH * 2);  // 16 MB
  float* X1 = (float*)take((size_t)ROWS * E_DIM * 4);            // 16 MB
  short* FF = (short*)take((size_t)ROWS * DFF_DIM * 2);          // 32 MB
  short* Kh = KVb;
  short* VTh = KVb + (size_t)B_SZ * NH * L_SEQ * DH;
  // attention split-KV partials: alias X1+FF (dead during attn; X1,FF
  // contiguous). OP 40 MB + RS 0.64 MB, consumed by attn_merge before
  // Pwo / X1 / FF re-use the space.
  float* OP = (float*)X1;
  float* RS = OP + (size_t)B_SZ * NH * NCID * 64 * 64;
  // split-K partial buffers (32 MB each):
  float* Pwo = (float*)FF;     // live: Wo gemm -> resid_rms_fused
  float* Pwout = (float*)QKV;  // spans QKV+CTX, dead after attn/Wo
  (void)ws_size;
  (void)in_sizes;
  (void)n_in;
  (void)out_size;

  dim3 blk(256);
  prep_all<<<16384 + ROWS, blk, 0, stream>>>(Wqkv, Wo_sa, Ww, Wv, Wout, X,
                                             WqkvT, WoT, Bcat, WoutT, Hbuf);
  gemm_bt<<<dim3(3072 / 128, ROWS / 128), blk, 0, stream>>>(
      Hbuf, WqkvT, bqkv, nullptr, QKV, ROWS, 3072, 1024, 0, 1);
  kv_prep<<<dim3(L_SEQ / 64, B_SZ * NH), blk, 0, stream>>>(QKV, Kh, VTh);
  attn_k<<<dim3(NCID, B_SZ * NH), blk, 0, stream>>>(QKV, Kh, VTh, OP, RS);
  attn_merge<<<ROWS, blk, 0, stream>>>(OP, RS, CTX);
  gemm_bt<<<dim3(1024 / 128, ROWS / 128, 2), blk, 0, stream>>>(
      CTX, WoT, nullptr, nullptr, Pwo, ROWS, 1024, 1024, 4, 2);
  resid_rms_fused<<<ROWS, blk, 0, stream>>>(
      X, Pwo, Pwo + (size_t)ROWS * E_DIM, bo_sa, X1, Hbuf);
  gemm_bt<<<dim3(2 * DFF_DIM / 128, ROWS / 128), blk, 0, stream>>>(
      Hbuf, Bcat, nullptr, nullptr, FF, ROWS, 2 * DFF_DIM, 1024, 5, 1);
  gemm_bt<<<dim3(1024 / 128, ROWS / 128, 2), blk, 0, stream>>>(
      FF, WoutT, nullptr, nullptr, Pwout, ROWS, 1024, 4096, 4, 2);
  add2_k<<<ROWS * E_DIM / (256 * 4), blk, 0, stream>>>(
      X1, Pwout, Pwout + (size_t)ROWS * E_DIM, (float*)d_out);
}